// Round 1
// baseline (649.764 us; speedup 1.0000x reference)
//
#include <hip/hip_runtime.h>
#include <hip/hip_bf16.h>
#include <math.h>

#define H_    16
#define S_    2048
#define D_    2048
#define DH_   128
#define DHID_ 256
#define DKER_ 128

typedef __attribute__((ext_vector_type(8))) short short8v;
typedef __attribute__((ext_vector_type(4))) float float4v;

static __device__ __forceinline__ short f2bf(float x){
  union { float f; unsigned u; } v; v.f = x;
  unsigned r = v.u + 0x7fffu + ((v.u >> 16) & 1u);   // RNE
  return (short)(r >> 16);
}
static __device__ __forceinline__ float gelu_f(float x){
  return 0.5f * x * (1.0f + erff(x * 0.70710678118654752440f));
}
static __device__ __forceinline__ float4v mfma16(short8v a, short8v b, float4v c){
  return __builtin_amdgcn_mfma_f32_16x16x32_bf16(a, b, c, 0, 0, 0);
}

// ---------------------------------------------------------------------------
// Mask dtype detection: 0=int32, 1=byte, 2=float32, 3=int64
__global__ void detect_mask_kernel(const unsigned int* mw, int* flag){
  int t = threadIdx.x;
  int bin = 1, f32ok = 1, odd0 = 1;
  for (int i = t; i < 1024; i += 256){
    unsigned w = mw[i];
    if (w > 1u) bin = 0;
    if (w != 0u && w != 0x3F800000u) f32ok = 0;
    if ((i & 1) && w != 0u) odd0 = 0;
  }
  __shared__ int sb, sf, so;
  if (t == 0){ sb = 1; sf = 1; so = 1; }
  __syncthreads();
  if (!bin)  atomicAnd(&sb, 0);
  if (!f32ok) atomicAnd(&sf, 0);
  if (!odd0) atomicAnd(&so, 0);
  __syncthreads();
  if (t == 0) *flag = sb ? (so ? 3 : 0) : (sf ? 2 : 1);
}

// Bit-pack mask: word w covers elements [w*32, w*32+32), bit b = element w*32+b
__global__ void pack_mask_kernel(const void* __restrict__ mask,
                                 const int* __restrict__ flagp,
                                 unsigned* __restrict__ MP){
  int flag = *flagp;
  size_t w = (size_t)blockIdx.x * blockDim.x + threadIdx.x;
  size_t base = w * 32;
  unsigned bits = 0;
  if (flag == 0){
    const int* m = (const int*)mask;
    #pragma unroll
    for (int b = 0; b < 32; ++b) bits |= (m[base + b] != 0 ? 1u : 0u) << b;
  } else if (flag == 1){
    const unsigned char* m = (const unsigned char*)mask;
    #pragma unroll
    for (int b = 0; b < 32; ++b) bits |= (m[base + b] != 0 ? 1u : 0u) << b;
  } else if (flag == 2){
    const float* m = (const float*)mask;
    #pragma unroll
    for (int b = 0; b < 32; ++b) bits |= (m[base + b] != 0.0f ? 1u : 0u) << b;
  } else {
    const int* m = (const int*)mask;   // int64: low word at 2*idx (LE)
    #pragma unroll
    for (int b = 0; b < 32; ++b) bits |= (m[2*(base + b)] != 0 ? 1u : 0u) << b;
  }
  MP[w] = bits;
}

// ---------------------------------------------------------------------------
// Generic transpose: src [B][R][C] f32 -> dst [B][C][R] bf16
__global__ void transpose_bf16_kernel(const float* __restrict__ src,
                                      short* __restrict__ dst, int R, int C){
  __shared__ float tile[32][33];
  int b  = blockIdx.z;
  int c0 = blockIdx.x * 32, r0 = blockIdx.y * 32;
  int tx = threadIdx.x, ty = threadIdx.y;           // 32 x 8
  const float* s = src + (size_t)b * R * C;
  short* d = dst + (size_t)b * R * C;
  #pragma unroll
  for (int i = 0; i < 32; i += 8)
    tile[ty + i][tx] = s[(size_t)(r0 + ty + i) * C + (c0 + tx)];
  __syncthreads();
  #pragma unroll
  for (int i = 0; i < 32; i += 8)
    d[(size_t)(c0 + ty + i) * R + (r0 + tx)] = f2bf(tile[tx][ty + i]);
}

// ---------------------------------------------------------------------------
// feat1: Y[h][s][0:256] = gelu( X[s, h*128:(h+1)*128] @ W1[h] )
// W1T bf16 [H][256][128]. Wave tile: 16 s-rows x 64 n-cols. block = 4 waves.
__global__ __launch_bounds__(256) void feat1_kernel(const float* __restrict__ X,
    const short* __restrict__ W1T, short* __restrict__ Y){
  int h = blockIdx.z;
  int lane = threadIdx.x & 63, warp = threadIdx.x >> 6;
  int s0 = (blockIdx.x * 4 + warp) * 16;
  int n0 = blockIdx.y * 64;
  int col = lane & 15, rg = lane >> 4;
  short8v a[4];
  {
    const float* xr = X + (size_t)(s0 + col) * D_ + h * DH_;
    #pragma unroll
    for (int kb = 0; kb < 4; ++kb){
      int k0 = kb * 32 + rg * 8;
      float4v x0 = *(const float4v*)(xr + k0);
      float4v x1 = *(const float4v*)(xr + k0 + 4);
      short8v t;
      t[0]=f2bf(x0[0]); t[1]=f2bf(x0[1]); t[2]=f2bf(x0[2]); t[3]=f2bf(x0[3]);
      t[4]=f2bf(x1[0]); t[5]=f2bf(x1[1]); t[6]=f2bf(x1[2]); t[7]=f2bf(x1[3]);
      a[kb] = t;
    }
  }
  const short* wbase = W1T + (size_t)h * DHID_ * DH_;
  short* yb = Y + ((size_t)h * S_ + s0) * DHID_;
  #pragma unroll
  for (int j = 0; j < 4; ++j){
    int n = n0 + j * 16;
    float4v c = {0.f, 0.f, 0.f, 0.f};
    const short* wr = wbase + (size_t)(n + col) * DH_ + rg * 8;
    #pragma unroll
    for (int kb = 0; kb < 4; ++kb)
      c = mfma16(a[kb], *(const short8v*)(wr + kb * 32), c);
    #pragma unroll
    for (int r = 0; r < 4; ++r)
      yb[(size_t)(rg * 4 + r) * DHID_ + n + col] = f2bf(gelu_f(c[r]));
  }
}

// feat2q: QF[h][s][0:128] = |gelu( Y @ W2q[h] )|   (bf16)
__global__ __launch_bounds__(256) void feat2q_kernel(const short* __restrict__ Y,
    const short* __restrict__ W2T, short* __restrict__ QF){
  int h = blockIdx.z;
  int lane = threadIdx.x & 63, warp = threadIdx.x >> 6;
  int s0 = (blockIdx.x * 4 + warp) * 16;
  int col = lane & 15, rg = lane >> 4;
  short8v a[8];
  const short* yr = Y + ((size_t)h * S_ + s0 + col) * DHID_ + rg * 8;
  #pragma unroll
  for (int kb = 0; kb < 8; ++kb) a[kb] = *(const short8v*)(yr + kb * 32);
  const short* wb = W2T + (size_t)h * DKER_ * DHID_;
  short* qb = QF + ((size_t)h * S_ + s0) * DKER_;
  #pragma unroll
  for (int j = 0; j < 8; ++j){
    int n = j * 16;
    float4v c = {0.f, 0.f, 0.f, 0.f};
    const short* wr = wb + (size_t)(n + col) * DHID_ + rg * 8;
    #pragma unroll
    for (int kb = 0; kb < 8; ++kb)
      c = mfma16(a[kb], *(const short8v*)(wr + kb * 32), c);
    #pragma unroll
    for (int r = 0; r < 4; ++r)
      qb[(size_t)(rg * 4 + r) * DKER_ + n + col] = f2bf(fabsf(gelu_f(c[r])));
  }
}

// feat2k: kf0 = |sD| * gelu(Y @ W2k);  KF = | kf0 + (kf0 @ IK) * sD2 |  (bf16)
__global__ __launch_bounds__(256) void feat2k_kernel(const short* __restrict__ Y,
    const short* __restrict__ W2T, const short* __restrict__ IKT,
    const float* __restrict__ sD, const float* __restrict__ sD2,
    short* __restrict__ KF){
  __shared__ __align__(16) short kls[4][16][136];   // 128 + 8 pad
  int h = blockIdx.z;
  int lane = threadIdx.x & 63, warp = threadIdx.x >> 6;
  int s0 = (blockIdx.x * 4 + warp) * 16;
  int col = lane & 15, rg = lane >> 4;
  short8v a[8];
  const short* yr = Y + ((size_t)h * S_ + s0 + col) * DHID_ + rg * 8;
  #pragma unroll
  for (int kb = 0; kb < 8; ++kb) a[kb] = *(const short8v*)(yr + kb * 32);
  const short* wb = W2T + (size_t)h * DKER_ * DHID_;
  float kf0[8][4];
  #pragma unroll
  for (int j = 0; j < 8; ++j){
    int n = j * 16;
    float4v c = {0.f, 0.f, 0.f, 0.f};
    const short* wr = wb + (size_t)(n + col) * DHID_ + rg * 8;
    #pragma unroll
    for (int kb = 0; kb < 8; ++kb)
      c = mfma16(a[kb], *(const short8v*)(wr + kb * 32), c);
    float sc = fabsf(sD[h * DKER_ + n + col]);
    #pragma unroll
    for (int r = 0; r < 4; ++r){
      float v = sc * gelu_f(c[r]);
      kf0[j][r] = v;
      kls[warp][rg * 4 + r][n + col] = f2bf(v);
    }
  }
  __syncthreads();
  short8v pa[4];
  #pragma unroll
  for (int kb = 0; kb < 4; ++kb)
    pa[kb] = *(const short8v*)(&kls[warp][col][kb * 32 + rg * 8]);
  const short* ib = IKT + (size_t)h * DKER_ * DKER_;
  short* ko = KF + ((size_t)h * S_ + s0) * DKER_;
  #pragma unroll
  for (int j = 0; j < 8; ++j){
    int n = j * 16;
    float4v c = {0.f, 0.f, 0.f, 0.f};
    const short* ir = ib + (size_t)(n + col) * DKER_ + rg * 8;
    #pragma unroll
    for (int kb = 0; kb < 4; ++kb)
      c = mfma16(pa[kb], *(const short8v*)(ir + kb * 32), c);
    float s2 = sD2[h * DKER_ + n + col];
    #pragma unroll
    for (int r = 0; r < 4; ++r)
      ko[(size_t)(rg * 4 + r) * DKER_ + n + col] = f2bf(fabsf(kf0[j][r] + c[r] * s2));
  }
}

// ---------------------------------------------------------------------------
// Fused main pass. Per wave: 16 s-rows of one head.
//   scores(s,t) = qf(s,:)·kf(t,:)           [MFMA, K=128]
//   p = m ? scores + 1e-6 : exp(sparse_w);  R += m ? scores : 0
//   U += p @ V                              [MFMA via LDS transpose of p]
//   out = U * exp(-logaddexp(log(R+1e-6), lse))
__global__ __launch_bounds__(256) void main_attn_kernel(
    const short* __restrict__ QF, const short* __restrict__ KF,
    const short* __restrict__ VT, const unsigned* __restrict__ MP,
    const float* __restrict__ SW, const float* __restrict__ LSE,
    float* __restrict__ OUT){
  __shared__ __align__(16) short pls[2][4][16][40];  // [dbuf][warp][row][32 + 8 pad]
  int h = blockIdx.y;
  int lane = threadIdx.x & 63, warp = threadIdx.x >> 6;
  int s0 = (blockIdx.x * 4 + warp) * 16;
  int col = lane & 15, rg = lane >> 4;

  short8v qa[4];
  const short* qr = QF + ((size_t)h * S_ + s0 + col) * DKER_ + rg * 8;
  #pragma unroll
  for (int kb = 0; kb < 4; ++kb) qa[kb] = *(const short8v*)(qr + kb * 32);

  float4v acc[8];
  #pragma unroll
  for (int j = 0; j < 8; ++j) acc[j] = (float4v){0.f, 0.f, 0.f, 0.f};
  float rsum[4] = {0.f, 0.f, 0.f, 0.f};

  const short* kfb = KF + (size_t)h * S_ * DKER_ + rg * 8;
  const float* swb = SW + ((size_t)h * S_ + s0) * S_;
  const unsigned* mpb = MP + ((size_t)h * S_ + s0) * (S_ / 32);
  const short* vtb = VT + (size_t)h * DH_ * S_;

  for (int t0 = 0; t0 < S_; t0 += 32){
    int buf = (t0 >> 5) & 1;
    unsigned mw[4];
    #pragma unroll
    for (int r = 0; r < 4; ++r)
      mw[r] = mpb[(size_t)(rg * 4 + r) * (S_ / 32) + (t0 >> 5)];

    #pragma unroll
    for (int tt = 0; tt < 2; ++tt){
      int t1 = t0 + tt * 16;
      float4v c = {0.f, 0.f, 0.f, 0.f};
      const short* kr = kfb + (size_t)(t1 + col) * DKER_;
      #pragma unroll
      for (int kb = 0; kb < 4; ++kb)
        c = mfma16(qa[kb], *(const short8v*)(kr + kb * 32), c);
      #pragma unroll
      for (int r = 0; r < 4; ++r){
        bool m = (mw[r] >> (tt * 16 + col)) & 1u;
        float sw = swb[(size_t)(rg * 4 + r) * S_ + (t1 + col)];
        float p = m ? (c[r] + 1e-6f) : expf(sw);
        if (m) rsum[r] += c[r];
        pls[buf][warp][rg * 4 + r][tt * 16 + col] = f2bf(p);
      }
    }
    __syncthreads();
    short8v pa = *(const short8v*)(&pls[buf][warp][col][rg * 8]);
    const short* vb = vtb + t0 + rg * 8;
    #pragma unroll
    for (int j = 0; j < 8; ++j)
      acc[j] = mfma16(pa, *(const short8v*)(vb + (size_t)(j * 16 + col) * S_), acc[j]);
  }

  #pragma unroll
  for (int r = 0; r < 4; ++r){
    float v = rsum[r];
    v += __shfl_xor(v, 1); v += __shfl_xor(v, 2);
    v += __shfl_xor(v, 4); v += __shfl_xor(v, 8);
    rsum[r] = v;
  }
  float scale[4];
  #pragma unroll
  for (int r = 0; r < 4; ++r){
    int srow = s0 + rg * 4 + r;
    float a = logf(rsum[r] + 1e-6f);
    float b = LSE[h * S_ + srow];
    float mx = fmaxf(a, b);
    float norm = mx + log1pf(expf(-fabsf(a - b)));
    scale[r] = expf(-norm);
  }
  float* ob = OUT + (size_t)s0 * D_ + h * DH_;
  #pragma unroll
  for (int j = 0; j < 8; ++j)
    #pragma unroll
    for (int r = 0; r < 4; ++r)
      ob[(size_t)(rg * 4 + r) * D_ + j * 16 + col] = acc[j][r] * scale[r];
}

// ---------------------------------------------------------------------------
extern "C" void kernel_launch(void* const* d_in, const int* in_sizes, int n_in,
                              void* d_out, int out_size, void* d_ws, size_t ws_size,
                              hipStream_t stream){
  (void)in_sizes; (void)n_in; (void)out_size; (void)ws_size;
  const float* q   = (const float*)d_in[1];
  const float* k   = (const float*)d_in[2];
  const float* v   = (const float*)d_in[3];
  const void*  msk = d_in[4];
  const float* lse = (const float*)d_in[5];
  const float* sw  = (const float*)d_in[6];
  const float* w1q = (const float*)d_in[8];
  const float* w1k = (const float*)d_in[9];
  const float* w2q = (const float*)d_in[10];
  const float* w2k = (const float*)d_in[11];
  const float* ik  = (const float*)d_in[12];
  const float* sD  = (const float*)d_in[13];
  const float* sD2 = (const float*)d_in[14];
  float* out = (float*)d_out;

  char* ws = (char*)d_ws;
  size_t o = 0;
  int*   flag = (int*)(ws);            o += 256;
  short* W1qT = (short*)(ws + o);      o += (size_t)H_ * DHID_ * DH_ * 2;
  short* W1kT = (short*)(ws + o);      o += (size_t)H_ * DHID_ * DH_ * 2;
  short* W2qT = (short*)(ws + o);      o += (size_t)H_ * DKER_ * DHID_ * 2;
  short* W2kT = (short*)(ws + o);      o += (size_t)H_ * DKER_ * DHID_ * 2;
  short* IKT  = (short*)(ws + o);      o += (size_t)H_ * DKER_ * DKER_ * 2;
  short* VT   = (short*)(ws + o);      o += (size_t)S_ * D_ * 2;          // 8 MB
  short* QFb  = (short*)(ws + o);      o += (size_t)H_ * S_ * DKER_ * 2;  // 8 MB
  short* KFb  = (short*)(ws + o);      o += (size_t)H_ * S_ * DKER_ * 2;  // 8 MB
  unsigned* MP = (unsigned*)(ws + o);  o += (size_t)H_ * S_ * (S_/32) * 4;// 8 MB
  short* Y = (short*)d_out;            // 16 MB scratch, overwritten by main pass

  detect_mask_kernel<<<1, 256, 0, stream>>>((const unsigned int*)msk, flag);
  pack_mask_kernel<<<(H_*S_*(S_/32))/256, 256, 0, stream>>>(msk, flag, MP);

  dim3 tb(32, 8);
  transpose_bf16_kernel<<<dim3(DHID_/32, DH_/32, H_), tb, 0, stream>>>(w1q, W1qT, DH_, DHID_);
  transpose_bf16_kernel<<<dim3(DHID_/32, DH_/32, H_), tb, 0, stream>>>(w1k, W1kT, DH_, DHID_);
  transpose_bf16_kernel<<<dim3(DKER_/32, DHID_/32, H_), tb, 0, stream>>>(w2q, W2qT, DHID_, DKER_);
  transpose_bf16_kernel<<<dim3(DKER_/32, DHID_/32, H_), tb, 0, stream>>>(w2k, W2kT, DHID_, DKER_);
  transpose_bf16_kernel<<<dim3(DKER_/32, DKER_/32, H_), tb, 0, stream>>>(ik,  IKT,  DKER_, DKER_);
  transpose_bf16_kernel<<<dim3(D_/32, S_/32, 1), tb, 0, stream>>>(v, VT, S_, D_);

  feat1_kernel<<<dim3(S_/64, DHID_/64, H_), 256, 0, stream>>>(q, W1qT, Y);
  feat2q_kernel<<<dim3(S_/64, 1, H_), 256, 0, stream>>>(Y, W2qT, QFb);
  feat1_kernel<<<dim3(S_/64, DHID_/64, H_), 256, 0, stream>>>(k, W1kT, Y);
  feat2k_kernel<<<dim3(S_/64, 1, H_), 256, 0, stream>>>(Y, W2kT, IKT, sD, sD2, KFb);

  main_attn_kernel<<<dim3(S_/64, H_), 256, 0, stream>>>(QFb, KFb, VT, MP, sw, lse, out);
}

// Round 2
// 477.494 us; speedup vs baseline: 1.3608x; 1.3608x over previous
//
#include <hip/hip_runtime.h>
#include <hip/hip_bf16.h>
#include <math.h>

#define H_    16
#define S_    2048
#define D_    2048
#define DH_   128
#define DHID_ 256
#define DKER_ 128

typedef __attribute__((ext_vector_type(8))) short short8v;
typedef __attribute__((ext_vector_type(4))) float float4v;

static __device__ __forceinline__ short f2bf(float x){
  union { float f; unsigned u; } v; v.f = x;
  unsigned r = v.u + 0x7fffu + ((v.u >> 16) & 1u);   // RNE
  return (short)(r >> 16);
}
static __device__ __forceinline__ float gelu_f(float x){
  return 0.5f * x * (1.0f + erff(x * 0.70710678118654752440f));
}
static __device__ __forceinline__ float4v mfma16(short8v a, short8v b, float4v c){
  return __builtin_amdgcn_mfma_f32_16x16x32_bf16(a, b, c, 0, 0, 0);
}

// ---------------------------------------------------------------------------
// Mask dtype detection: 0=int32, 1=byte, 2=float32, 3=int64
__global__ void detect_mask_kernel(const unsigned int* mw, int* flag){
  int t = threadIdx.x;
  int bin = 1, f32ok = 1, odd0 = 1;
  for (int i = t; i < 1024; i += 256){
    unsigned w = mw[i];
    if (w > 1u) bin = 0;
    if (w != 0u && w != 0x3F800000u) f32ok = 0;
    if ((i & 1) && w != 0u) odd0 = 0;
  }
  __shared__ int sb, sf, so;
  if (t == 0){ sb = 1; sf = 1; so = 1; }
  __syncthreads();
  if (!bin)  atomicAnd(&sb, 0);
  if (!f32ok) atomicAnd(&sf, 0);
  if (!odd0) atomicAnd(&so, 0);
  __syncthreads();
  if (t == 0) *flag = sb ? (so ? 3 : 0) : (sf ? 2 : 1);
}

// Bit-pack mask: word w covers elements [w*32, w*32+32), bit b = element w*32+b
__global__ void pack_mask_kernel(const void* __restrict__ mask,
                                 const int* __restrict__ flagp,
                                 unsigned* __restrict__ MP){
  int flag = *flagp;
  size_t w = (size_t)blockIdx.x * blockDim.x + threadIdx.x;
  size_t base = w * 32;
  unsigned bits = 0;
  if (flag == 0){
    const int* m = (const int*)mask;
    #pragma unroll
    for (int b = 0; b < 32; ++b) bits |= (m[base + b] != 0 ? 1u : 0u) << b;
  } else if (flag == 1){
    const unsigned char* m = (const unsigned char*)mask;
    #pragma unroll
    for (int b = 0; b < 32; ++b) bits |= (m[base + b] != 0 ? 1u : 0u) << b;
  } else if (flag == 2){
    const float* m = (const float*)mask;
    #pragma unroll
    for (int b = 0; b < 32; ++b) bits |= (m[base + b] != 0.0f ? 1u : 0u) << b;
  } else {
    const int* m = (const int*)mask;   // int64: low word at 2*idx (LE)
    #pragma unroll
    for (int b = 0; b < 32; ++b) bits |= (m[2*(base + b)] != 0 ? 1u : 0u) << b;
  }
  MP[w] = bits;
}

// ---------------------------------------------------------------------------
// Generic transpose: src [B][R][C] f32 -> dst [B][C][R] bf16
__global__ void transpose_bf16_kernel(const float* __restrict__ src,
                                      short* __restrict__ dst, int R, int C){
  __shared__ float tile[32][33];
  int b  = blockIdx.z;
  int c0 = blockIdx.x * 32, r0 = blockIdx.y * 32;
  int tx = threadIdx.x, ty = threadIdx.y;           // 32 x 8
  const float* s = src + (size_t)b * R * C;
  short* d = dst + (size_t)b * R * C;
  #pragma unroll
  for (int i = 0; i < 32; i += 8)
    tile[ty + i][tx] = s[(size_t)(r0 + ty + i) * C + (c0 + tx)];
  __syncthreads();
  #pragma unroll
  for (int i = 0; i < 32; i += 8)
    d[(size_t)(c0 + ty + i) * R + (r0 + tx)] = f2bf(tile[tx][ty + i]);
}

// ---------------------------------------------------------------------------
// feat1: Y[h][s][0:256] = gelu( X[s, h*128:(h+1)*128] @ W1[h] )
__global__ __launch_bounds__(256) void feat1_kernel(const float* __restrict__ X,
    const short* __restrict__ W1T, short* __restrict__ Y){
  int h = blockIdx.z;
  int lane = threadIdx.x & 63, warp = threadIdx.x >> 6;
  int s0 = (blockIdx.x * 4 + warp) * 16;
  int n0 = blockIdx.y * 64;
  int col = lane & 15, rg = lane >> 4;
  short8v a[4];
  {
    const float* xr = X + (size_t)(s0 + col) * D_ + h * DH_;
    #pragma unroll
    for (int kb = 0; kb < 4; ++kb){
      int k0 = kb * 32 + rg * 8;
      float4v x0 = *(const float4v*)(xr + k0);
      float4v x1 = *(const float4v*)(xr + k0 + 4);
      short8v t;
      t[0]=f2bf(x0[0]); t[1]=f2bf(x0[1]); t[2]=f2bf(x0[2]); t[3]=f2bf(x0[3]);
      t[4]=f2bf(x1[0]); t[5]=f2bf(x1[1]); t[6]=f2bf(x1[2]); t[7]=f2bf(x1[3]);
      a[kb] = t;
    }
  }
  const short* wbase = W1T + (size_t)h * DHID_ * DH_;
  short* yb = Y + ((size_t)h * S_ + s0) * DHID_;
  #pragma unroll
  for (int j = 0; j < 4; ++j){
    int n = n0 + j * 16;
    float4v c = {0.f, 0.f, 0.f, 0.f};
    const short* wr = wbase + (size_t)(n + col) * DH_ + rg * 8;
    #pragma unroll
    for (int kb = 0; kb < 4; ++kb)
      c = mfma16(a[kb], *(const short8v*)(wr + kb * 32), c);
    #pragma unroll
    for (int r = 0; r < 4; ++r)
      yb[(size_t)(rg * 4 + r) * DHID_ + n + col] = f2bf(gelu_f(c[r]));
  }
}

// feat2q: QF[h][s][0:128] = |gelu( Y @ W2q[h] )|   (bf16)
__global__ __launch_bounds__(256) void feat2q_kernel(const short* __restrict__ Y,
    const short* __restrict__ W2T, short* __restrict__ QF){
  int h = blockIdx.z;
  int lane = threadIdx.x & 63, warp = threadIdx.x >> 6;
  int s0 = (blockIdx.x * 4 + warp) * 16;
  int col = lane & 15, rg = lane >> 4;
  short8v a[8];
  const short* yr = Y + ((size_t)h * S_ + s0 + col) * DHID_ + rg * 8;
  #pragma unroll
  for (int kb = 0; kb < 8; ++kb) a[kb] = *(const short8v*)(yr + kb * 32);
  const short* wb = W2T + (size_t)h * DKER_ * DHID_;
  short* qb = QF + ((size_t)h * S_ + s0) * DKER_;
  #pragma unroll
  for (int j = 0; j < 8; ++j){
    int n = j * 16;
    float4v c = {0.f, 0.f, 0.f, 0.f};
    const short* wr = wb + (size_t)(n + col) * DHID_ + rg * 8;
    #pragma unroll
    for (int kb = 0; kb < 8; ++kb)
      c = mfma16(a[kb], *(const short8v*)(wr + kb * 32), c);
    #pragma unroll
    for (int r = 0; r < 4; ++r)
      qb[(size_t)(rg * 4 + r) * DKER_ + n + col] = f2bf(fabsf(gelu_f(c[r])));
  }
}

// feat2k: kf0 = |sD| * gelu(Y @ W2k);  KF = | kf0 + (kf0 @ IK) * sD2 |  (bf16)
__global__ __launch_bounds__(256) void feat2k_kernel(const short* __restrict__ Y,
    const short* __restrict__ W2T, const short* __restrict__ IKT,
    const float* __restrict__ sD, const float* __restrict__ sD2,
    short* __restrict__ KF){
  __shared__ __align__(16) short kls[4][16][136];
  int h = blockIdx.z;
  int lane = threadIdx.x & 63, warp = threadIdx.x >> 6;
  int s0 = (blockIdx.x * 4 + warp) * 16;
  int col = lane & 15, rg = lane >> 4;
  short8v a[8];
  const short* yr = Y + ((size_t)h * S_ + s0 + col) * DHID_ + rg * 8;
  #pragma unroll
  for (int kb = 0; kb < 8; ++kb) a[kb] = *(const short8v*)(yr + kb * 32);
  const short* wb = W2T + (size_t)h * DKER_ * DHID_;
  float kf0[8][4];
  #pragma unroll
  for (int j = 0; j < 8; ++j){
    int n = j * 16;
    float4v c = {0.f, 0.f, 0.f, 0.f};
    const short* wr = wb + (size_t)(n + col) * DHID_ + rg * 8;
    #pragma unroll
    for (int kb = 0; kb < 8; ++kb)
      c = mfma16(a[kb], *(const short8v*)(wr + kb * 32), c);
    float sc = fabsf(sD[h * DKER_ + n + col]);
    #pragma unroll
    for (int r = 0; r < 4; ++r){
      float v = sc * gelu_f(c[r]);
      kf0[j][r] = v;
      kls[warp][rg * 4 + r][n + col] = f2bf(v);
    }
  }
  __syncthreads();
  short8v pa[4];
  #pragma unroll
  for (int kb = 0; kb < 4; ++kb)
    pa[kb] = *(const short8v*)(&kls[warp][col][kb * 32 + rg * 8]);
  const short* ib = IKT + (size_t)h * DKER_ * DKER_;
  short* ko = KF + ((size_t)h * S_ + s0) * DKER_;
  #pragma unroll
  for (int j = 0; j < 8; ++j){
    int n = j * 16;
    float4v c = {0.f, 0.f, 0.f, 0.f};
    const short* ir = ib + (size_t)(n + col) * DKER_ + rg * 8;
    #pragma unroll
    for (int kb = 0; kb < 4; ++kb)
      c = mfma16(pa[kb], *(const short8v*)(ir + kb * 32), c);
    float s2 = sD2[h * DKER_ + n + col];
    #pragma unroll
    for (int r = 0; r < 4; ++r)
      ko[(size_t)(rg * 4 + r) * DKER_ + n + col] = f2bf(fabsf(kf0[j][r] + c[r] * s2));
  }
}

// ---------------------------------------------------------------------------
// Fused main pass, t-split. Per wave: 16 s-rows of one head, t-chunk of S/nsplit.
// P-buffer prefilled with bf16(exp(sw)) via coalesced float4 loads; masked-1
// slots overwritten with bf16(score + 1e-6). Warps are independent (no barrier).
__global__ __launch_bounds__(256, 4) void main_attn_kernel(
    const short* __restrict__ QF, const short* __restrict__ KF,
    const short* __restrict__ VT, const unsigned* __restrict__ MP,
    const float* __restrict__ SW, const float* __restrict__ LSE,
    float* __restrict__ OUT, float* __restrict__ PU, float* __restrict__ PR,
    int nsplit){
  __shared__ __align__(16) short pls[4][16][40];   // per-warp [16 rows][32+8 pad]
  int lane = threadIdx.x & 63, warp = threadIdx.x >> 6;
  // XCD-chunked swizzle of the 512 (sblk,h) pairs (bijective: 512 % 8 == 0)
  int flat = blockIdx.y * 32 + blockIdx.x;
  int nf = (flat & 7) * 64 + (flat >> 3);
  int sblk = nf & 31, h = nf >> 5;
  int split = blockIdx.z;
  int niter = (S_ / 32) / nsplit;
  int tbase = split * (S_ / nsplit);
  int s0 = (sblk * 4 + warp) * 16;
  int col = lane & 15, rg = lane >> 4;
  int prow = lane >> 2, pcs = lane & 3;            // prefill mapping

  short8v qa[4];
  const short* qr = QF + ((size_t)h * S_ + s0 + col) * DKER_ + rg * 8;
  #pragma unroll
  for (int kb = 0; kb < 4; ++kb) qa[kb] = *(const short8v*)(qr + kb * 32);

  float4v acc[8];
  #pragma unroll
  for (int j = 0; j < 8; ++j) acc[j] = (float4v){0.f, 0.f, 0.f, 0.f};
  float rsum[4] = {0.f, 0.f, 0.f, 0.f};

  const short* kfb = KF + (size_t)h * S_ * DKER_ + rg * 8;
  const float* swp = SW + ((size_t)h * S_ + s0 + prow) * S_ + tbase + pcs * 8;
  const unsigned* mpb = MP + ((size_t)h * S_ + s0) * (S_ / 32) + (tbase >> 5);
  const short* vtb = VT + (size_t)h * DH_ * S_ + tbase;

  for (int ti = 0; ti < niter; ++ti){
    int t0 = tbase + ti * 32;
    // --- prefill P with exp(sw), coalesced ---
    float4v sv0 = *(const float4v*)(swp + ti * 32);
    float4v sv1 = *(const float4v*)(swp + ti * 32 + 4);
    short8v pf;
    pf[0] = f2bf(expf(sv0[0])); pf[1] = f2bf(expf(sv0[1]));
    pf[2] = f2bf(expf(sv0[2])); pf[3] = f2bf(expf(sv0[3]));
    pf[4] = f2bf(expf(sv1[0])); pf[5] = f2bf(expf(sv1[1]));
    pf[6] = f2bf(expf(sv1[2])); pf[7] = f2bf(expf(sv1[3]));
    *(short8v*)(&pls[warp][prow][pcs * 8]) = pf;

    unsigned mw[4];
    #pragma unroll
    for (int r = 0; r < 4; ++r)
      mw[r] = mpb[(size_t)(rg * 4 + r) * (S_ / 32) + ti];

    // --- scores; overwrite masked-1 slots ---
    #pragma unroll
    for (int tt = 0; tt < 2; ++tt){
      float4v c = {0.f, 0.f, 0.f, 0.f};
      const short* kr = kfb + (size_t)(t0 + tt * 16 + col) * DKER_;
      #pragma unroll
      for (int kb = 0; kb < 4; ++kb)
        c = mfma16(qa[kb], *(const short8v*)(kr + kb * 32), c);
      #pragma unroll
      for (int r = 0; r < 4; ++r){
        if ((mw[r] >> (tt * 16 + col)) & 1u){
          rsum[r] += c[r];
          pls[warp][rg * 4 + r][tt * 16 + col] = f2bf(c[r] + 1e-6f);
        }
      }
    }
    // LDS ops of a wave complete in order; drain, then read P back
    asm volatile("s_waitcnt lgkmcnt(0)" ::: "memory");
    __builtin_amdgcn_sched_barrier(0);
    short8v pa = *(const short8v*)(&pls[warp][col][rg * 8]);
    const short* vb = vtb + ti * 32 + rg * 8;
    #pragma unroll
    for (int j = 0; j < 8; ++j)
      acc[j] = mfma16(pa, *(const short8v*)(vb + (size_t)(j * 16 + col) * S_), acc[j]);
    asm volatile("" ::: "memory");   // keep next prefill after the pa read
  }

  #pragma unroll
  for (int r = 0; r < 4; ++r){
    float v = rsum[r];
    v += __shfl_xor(v, 1); v += __shfl_xor(v, 2);
    v += __shfl_xor(v, 4); v += __shfl_xor(v, 8);
    rsum[r] = v;
  }

  if (nsplit == 1){
    float scale[4];
    #pragma unroll
    for (int r = 0; r < 4; ++r){
      int srow = s0 + rg * 4 + r;
      float a = logf(rsum[r] + 1e-6f);
      float b = LSE[h * S_ + srow];
      float mx = fmaxf(a, b);
      float norm = mx + log1pf(expf(-fabsf(a - b)));
      scale[r] = expf(-norm);
    }
    float* ob = OUT + (size_t)s0 * D_ + h * DH_;
    #pragma unroll
    for (int j = 0; j < 8; ++j)
      #pragma unroll
      for (int r = 0; r < 4; ++r)
        ob[(size_t)(rg * 4 + r) * D_ + j * 16 + col] = acc[j][r] * scale[r];
  } else {
    float* pu = PU + (((size_t)split * H_ + h) * S_ + s0) * DH_;
    #pragma unroll
    for (int j = 0; j < 8; ++j)
      #pragma unroll
      for (int r = 0; r < 4; ++r)
        pu[(size_t)(rg * 4 + r) * DH_ + j * 16 + col] = acc[j][r];
    if (col == 0){
      #pragma unroll
      for (int r = 0; r < 4; ++r)
        PR[((size_t)split * H_ + h) * S_ + s0 + rg * 4 + r] = rsum[r];
    }
  }
}

// Combine split partials: out = (sum U) * exp(-logaddexp(log(sum R + 1e-6), lse))
__global__ __launch_bounds__(256) void reduce_kernel(
    const float* __restrict__ PU, const float* __restrict__ PR,
    const float* __restrict__ LSE, float* __restrict__ OUT, int nsplit){
  size_t gid = (size_t)blockIdx.x * 256 + threadIdx.x;   // over H*S*DH = 2^22
  int d = gid & (DH_ - 1);
  int s = (int)(gid >> 7) & (S_ - 1);
  int h = (int)(gid >> 18);
  float u = 0.f, rr = 0.f;
  for (int i = 0; i < nsplit; ++i){
    u  += PU[(((size_t)i * H_ + h) * S_ + s) * DH_ + d];
    rr += PR[((size_t)i * H_ + h) * S_ + s];
  }
  float a = logf(rr + 1e-6f);
  float b = LSE[h * S_ + s];
  float mx = fmaxf(a, b);
  float norm = mx + log1pf(expf(-fabsf(a - b)));
  OUT[(size_t)s * D_ + h * DH_ + d] = u * expf(-norm);
}

// ---------------------------------------------------------------------------
extern "C" void kernel_launch(void* const* d_in, const int* in_sizes, int n_in,
                              void* d_out, int out_size, void* d_ws, size_t ws_size,
                              hipStream_t stream){
  (void)in_sizes; (void)n_in; (void)out_size;
  const float* q   = (const float*)d_in[1];
  const float* k   = (const float*)d_in[2];
  const float* v   = (const float*)d_in[3];
  const void*  msk = d_in[4];
  const float* lse = (const float*)d_in[5];
  const float* sw  = (const float*)d_in[6];
  const float* w1q = (const float*)d_in[8];
  const float* w1k = (const float*)d_in[9];
  const float* w2q = (const float*)d_in[10];
  const float* w2k = (const float*)d_in[11];
  const float* ik  = (const float*)d_in[12];
  const float* sD  = (const float*)d_in[13];
  const float* sD2 = (const float*)d_in[14];
  float* out = (float*)d_out;

  char* ws = (char*)d_ws;
  size_t o = 0;
  int*   flag = (int*)(ws);            o += 256;
  short* W1qT = (short*)(ws + o);      o += (size_t)H_ * DHID_ * DH_ * 2;
  short* W1kT = (short*)(ws + o);      o += (size_t)H_ * DHID_ * DH_ * 2;
  short* W2qT = (short*)(ws + o);      o += (size_t)H_ * DKER_ * DHID_ * 2;
  short* W2kT = (short*)(ws + o);      o += (size_t)H_ * DKER_ * DHID_ * 2;
  short* IKT  = (short*)(ws + o);      o += (size_t)H_ * DKER_ * DKER_ * 2;
  short* VT   = (short*)(ws + o);      o += (size_t)S_ * D_ * 2;
  short* QFb  = (short*)(ws + o);      o += (size_t)H_ * S_ * DKER_ * 2;
  short* KFb  = (short*)(ws + o);      o += (size_t)H_ * S_ * DKER_ * 2;
  unsigned* MP = (unsigned*)(ws + o);  o += (size_t)H_ * S_ * (S_/32) * 4;
  short* Y = (short*)d_out;            // 16 MB scratch, overwritten later

  // choose t-split from available scratch (deterministic: ws_size is fixed)
  size_t per_split = (size_t)H_ * S_ * DH_ * 4 + (size_t)H_ * S_ * 4;
  int nsplit = 1;
  if (ws_size >= o + 4 * per_split)      nsplit = 4;
  else if (ws_size >= o + 2 * per_split) nsplit = 2;
  float* PU = (float*)(ws + o);
  float* PR = PU + (size_t)nsplit * H_ * S_ * DH_;

  detect_mask_kernel<<<1, 256, 0, stream>>>((const unsigned int*)msk, flag);
  pack_mask_kernel<<<(H_*S_*(S_/32))/256, 256, 0, stream>>>(msk, flag, MP);

  dim3 tb(32, 8);
  transpose_bf16_kernel<<<dim3(DHID_/32, DH_/32, H_), tb, 0, stream>>>(w1q, W1qT, DH_, DHID_);
  transpose_bf16_kernel<<<dim3(DHID_/32, DH_/32, H_), tb, 0, stream>>>(w1k, W1kT, DH_, DHID_);
  transpose_bf16_kernel<<<dim3(DKER_/32, DHID_/32, H_), tb, 0, stream>>>(w2q, W2qT, DHID_, DKER_);
  transpose_bf16_kernel<<<dim3(DKER_/32, DHID_/32, H_), tb, 0, stream>>>(w2k, W2kT, DHID_, DKER_);
  transpose_bf16_kernel<<<dim3(DKER_/32, DKER_/32, H_), tb, 0, stream>>>(ik,  IKT,  DKER_, DKER_);
  transpose_bf16_kernel<<<dim3(D_/32, S_/32, 1), tb, 0, stream>>>(v, VT, S_, D_);

  feat1_kernel<<<dim3(S_/64, DHID_/64, H_), 256, 0, stream>>>(q, W1qT, Y);
  feat2q_kernel<<<dim3(S_/64, 1, H_), 256, 0, stream>>>(Y, W2qT, QFb);
  feat1_kernel<<<dim3(S_/64, DHID_/64, H_), 256, 0, stream>>>(k, W1kT, Y);
  feat2k_kernel<<<dim3(S_/64, 1, H_), 256, 0, stream>>>(Y, W2kT, IKT, sD, sD2, KFb);

  main_attn_kernel<<<dim3(32, 16, nsplit), 256, 0, stream>>>(
      QFb, KFb, VT, MP, sw, lse, out, PU, PR, nsplit);
  if (nsplit > 1)
    reduce_kernel<<<(H_*S_*DH_)/256, 256, 0, stream>>>(PU, PR, lse, out, nsplit);
}

// Round 3
// 319.174 us; speedup vs baseline: 2.0358x; 1.4960x over previous
//
#include <hip/hip_runtime.h>
#include <hip/hip_bf16.h>
#include <math.h>

#define H_    16
#define S_    2048
#define D_    2048
#define DH_   128
#define DHID_ 256
#define DKER_ 128

typedef __attribute__((ext_vector_type(8))) short short8v;
typedef __attribute__((ext_vector_type(4))) float float4v;

static __device__ __forceinline__ short f2bf(float x){
  union { float f; unsigned u; } v; v.f = x;
  unsigned r = v.u + 0x7fffu + ((v.u >> 16) & 1u);   // RNE
  return (short)(r >> 16);
}
static __device__ __forceinline__ float gelu_f(float x){
  return 0.5f * x * (1.0f + erff(x * 0.70710678118654752440f));
}
static __device__ __forceinline__ float4v mfma16(short8v a, short8v b, float4v c){
  return __builtin_amdgcn_mfma_f32_16x16x32_bf16(a, b, c, 0, 0, 0);
}
static __device__ __forceinline__ unsigned cvtpk(float lo, float hi){
  unsigned d;
  asm("v_cvt_pk_bf16_f32 %0, %1, %2" : "=v"(d) : "v"(lo), "v"(hi));
  return d;
}
static __device__ __forceinline__ void glds16(const void* g, void* l){
  __builtin_amdgcn_global_load_lds(
      (const __attribute__((address_space(1))) void*)g,
      (__attribute__((address_space(3))) void*)l, 16, 0, 0);
}

// ---------------------------------------------------------------------------
// Mask dtype detection: 0=int32, 1=byte, 2=float32, 3=int64
__global__ void detect_mask_kernel(const unsigned int* mw, int* flag){
  int t = threadIdx.x;
  int bin = 1, f32ok = 1, odd0 = 1;
  for (int i = t; i < 1024; i += 256){
    unsigned w = mw[i];
    if (w > 1u) bin = 0;
    if (w != 0u && w != 0x3F800000u) f32ok = 0;
    if ((i & 1) && w != 0u) odd0 = 0;
  }
  __shared__ int sb, sf, so;
  if (t == 0){ sb = 1; sf = 1; so = 1; }
  __syncthreads();
  if (!bin)  atomicAnd(&sb, 0);
  if (!f32ok) atomicAnd(&sf, 0);
  if (!odd0) atomicAnd(&so, 0);
  __syncthreads();
  if (t == 0) *flag = sb ? (so ? 3 : 0) : (sf ? 2 : 1);
}

// Bit-pack mask: word w covers elements [w*32, w*32+32), bit b = element w*32+b
__global__ void pack_mask_kernel(const void* __restrict__ mask,
                                 const int* __restrict__ flagp,
                                 unsigned* __restrict__ MP){
  int flag = *flagp;
  size_t w = (size_t)blockIdx.x * blockDim.x + threadIdx.x;
  size_t base = w * 32;
  unsigned bits = 0;
  if (flag == 0){
    const int* m = (const int*)mask;
    #pragma unroll
    for (int b = 0; b < 32; ++b) bits |= (m[base + b] != 0 ? 1u : 0u) << b;
  } else if (flag == 1){
    const unsigned char* m = (const unsigned char*)mask;
    #pragma unroll
    for (int b = 0; b < 32; ++b) bits |= (m[base + b] != 0 ? 1u : 0u) << b;
  } else if (flag == 2){
    const float* m = (const float*)mask;
    #pragma unroll
    for (int b = 0; b < 32; ++b) bits |= (m[base + b] != 0.0f ? 1u : 0u) << b;
  } else {
    const int* m = (const int*)mask;   // int64: low word at 2*idx (LE)
    #pragma unroll
    for (int b = 0; b < 32; ++b) bits |= (m[2*(base + b)] != 0 ? 1u : 0u) << b;
  }
  MP[w] = bits;
}

// ---------------------------------------------------------------------------
// Generic transpose: src [B][R][C] f32 -> dst [B][C][R] bf16  (weights only)
__global__ void transpose_bf16_kernel(const float* __restrict__ src,
                                      short* __restrict__ dst, int R, int C){
  __shared__ float tile[32][33];
  int b  = blockIdx.z;
  int c0 = blockIdx.x * 32, r0 = blockIdx.y * 32;
  int tx = threadIdx.x, ty = threadIdx.y;           // 32 x 8
  const float* s = src + (size_t)b * R * C;
  short* d = dst + (size_t)b * R * C;
  #pragma unroll
  for (int i = 0; i < 32; i += 8)
    tile[ty + i][tx] = s[(size_t)(r0 + ty + i) * C + (c0 + tx)];
  __syncthreads();
  #pragma unroll
  for (int i = 0; i < 32; i += 8)
    d[(size_t)(c0 + ty + i) * R + (r0 + tx)] = f2bf(tile[tx][ty + i]);
}

// V2 layout: element (h, t, d) -> V2[((h*(S/8) + (t>>3))*DH + d)*8 + (t&7)]
// so a 32-t x 128-d tile is 8KB CONTIGUOUS (4 octets x [128 d][8 t] bf16).
__global__ __launch_bounds__(256) void transpose_v2_kernel(
    const float* __restrict__ v, short* __restrict__ V2){
  int h = blockIdx.y;
  int tid = threadIdx.x;
  int d = tid & 127, oct = tid >> 7;                // 2 octets per block
  int t8 = blockIdx.x * 2 + oct;
  const float* src = v + (size_t)(t8 * 8) * D_ + h * DH_ + d;
  short8v o;
  #pragma unroll
  for (int j = 0; j < 8; ++j) o[j] = f2bf(src[(size_t)j * D_]);
  *(short8v*)(V2 + (((size_t)h * (S_/8) + t8) * DH_ + d) * 8) = o;
}

// ---------------------------------------------------------------------------
// feat1: Y[h][s][0:256] = gelu( X[s, h*128:(h+1)*128] @ W1[h] )
__global__ __launch_bounds__(256) void feat1_kernel(const float* __restrict__ X,
    const short* __restrict__ W1T, short* __restrict__ Y){
  int h = blockIdx.z;
  int lane = threadIdx.x & 63, warp = threadIdx.x >> 6;
  int s0 = (blockIdx.x * 4 + warp) * 16;
  int n0 = blockIdx.y * 64;
  int col = lane & 15, rg = lane >> 4;
  short8v a[4];
  {
    const float* xr = X + (size_t)(s0 + col) * D_ + h * DH_;
    #pragma unroll
    for (int kb = 0; kb < 4; ++kb){
      int k0 = kb * 32 + rg * 8;
      float4v x0 = *(const float4v*)(xr + k0);
      float4v x1 = *(const float4v*)(xr + k0 + 4);
      short8v t;
      t[0]=f2bf(x0[0]); t[1]=f2bf(x0[1]); t[2]=f2bf(x0[2]); t[3]=f2bf(x0[3]);
      t[4]=f2bf(x1[0]); t[5]=f2bf(x1[1]); t[6]=f2bf(x1[2]); t[7]=f2bf(x1[3]);
      a[kb] = t;
    }
  }
  const short* wbase = W1T + (size_t)h * DHID_ * DH_;
  short* yb = Y + ((size_t)h * S_ + s0) * DHID_;
  #pragma unroll
  for (int j = 0; j < 4; ++j){
    int n = n0 + j * 16;
    float4v c = {0.f, 0.f, 0.f, 0.f};
    const short* wr = wbase + (size_t)(n + col) * DH_ + rg * 8;
    #pragma unroll
    for (int kb = 0; kb < 4; ++kb)
      c = mfma16(a[kb], *(const short8v*)(wr + kb * 32), c);
    #pragma unroll
    for (int r = 0; r < 4; ++r)
      yb[(size_t)(rg * 4 + r) * DHID_ + n + col] = f2bf(gelu_f(c[r]));
  }
}

// feat2q: QF[h][s][0:128] = |gelu( Y @ W2q[h] )|   (bf16)
__global__ __launch_bounds__(256) void feat2q_kernel(const short* __restrict__ Y,
    const short* __restrict__ W2T, short* __restrict__ QF){
  int h = blockIdx.z;
  int lane = threadIdx.x & 63, warp = threadIdx.x >> 6;
  int s0 = (blockIdx.x * 4 + warp) * 16;
  int col = lane & 15, rg = lane >> 4;
  short8v a[8];
  const short* yr = Y + ((size_t)h * S_ + s0 + col) * DHID_ + rg * 8;
  #pragma unroll
  for (int kb = 0; kb < 8; ++kb) a[kb] = *(const short8v*)(yr + kb * 32);
  const short* wb = W2T + (size_t)h * DKER_ * DHID_;
  short* qb = QF + ((size_t)h * S_ + s0) * DKER_;
  #pragma unroll
  for (int j = 0; j < 8; ++j){
    int n = j * 16;
    float4v c = {0.f, 0.f, 0.f, 0.f};
    const short* wr = wb + (size_t)(n + col) * DHID_ + rg * 8;
    #pragma unroll
    for (int kb = 0; kb < 8; ++kb)
      c = mfma16(a[kb], *(const short8v*)(wr + kb * 32), c);
    #pragma unroll
    for (int r = 0; r < 4; ++r)
      qb[(size_t)(rg * 4 + r) * DKER_ + n + col] = f2bf(fabsf(gelu_f(c[r])));
  }
}

// feat2k: kf0 = |sD| * gelu(Y @ W2k);  KF = | kf0 + (kf0 @ IK) * sD2 |  (bf16)
__global__ __launch_bounds__(256) void feat2k_kernel(const short* __restrict__ Y,
    const short* __restrict__ W2T, const short* __restrict__ IKT,
    const float* __restrict__ sD, const float* __restrict__ sD2,
    short* __restrict__ KF){
  __shared__ __align__(16) short kls[4][16][136];
  int h = blockIdx.z;
  int lane = threadIdx.x & 63, warp = threadIdx.x >> 6;
  int s0 = (blockIdx.x * 4 + warp) * 16;
  int col = lane & 15, rg = lane >> 4;
  short8v a[8];
  const short* yr = Y + ((size_t)h * S_ + s0 + col) * DHID_ + rg * 8;
  #pragma unroll
  for (int kb = 0; kb < 8; ++kb) a[kb] = *(const short8v*)(yr + kb * 32);
  const short* wb = W2T + (size_t)h * DKER_ * DHID_;
  float kf0[8][4];
  #pragma unroll
  for (int j = 0; j < 8; ++j){
    int n = j * 16;
    float4v c = {0.f, 0.f, 0.f, 0.f};
    const short* wr = wb + (size_t)(n + col) * DHID_ + rg * 8;
    #pragma unroll
    for (int kb = 0; kb < 8; ++kb)
      c = mfma16(a[kb], *(const short8v*)(wr + kb * 32), c);
    float sc = fabsf(sD[h * DKER_ + n + col]);
    #pragma unroll
    for (int r = 0; r < 4; ++r){
      float v = sc * gelu_f(c[r]);
      kf0[j][r] = v;
      kls[warp][rg * 4 + r][n + col] = f2bf(v);
    }
  }
  __syncthreads();
  short8v pa[4];
  #pragma unroll
  for (int kb = 0; kb < 4; ++kb)
    pa[kb] = *(const short8v*)(&kls[warp][col][kb * 32 + rg * 8]);
  const short* ib = IKT + (size_t)h * DKER_ * DKER_;
  short* ko = KF + ((size_t)h * S_ + s0) * DKER_;
  #pragma unroll
  for (int j = 0; j < 8; ++j){
    int n = j * 16;
    float4v c = {0.f, 0.f, 0.f, 0.f};
    const short* ir = ib + (size_t)(n + col) * DKER_ + rg * 8;
    #pragma unroll
    for (int kb = 0; kb < 4; ++kb)
      c = mfma16(pa[kb], *(const short8v*)(ir + kb * 32), c);
    float s2 = sD2[h * DKER_ + n + col];
    #pragma unroll
    for (int r = 0; r < 4; ++r)
      ko[(size_t)(rg * 4 + r) * DKER_ + n + col] = f2bf(fabsf(kf0[j][r] + c[r] * s2));
  }
}

// ---------------------------------------------------------------------------
// Fused main pass. Swapped QK (A=KF, B=QF) keeps P lane-local; PV A-fragment
// assembled via cvt_pk + 8 shfl. KF/V tiles LDS-staged (global_load_lds,
// double-buffered, shared by 4 warps). KF LDS uses XOR-16 swizzle applied via
// pre-swizzled global source; V2 pre-transposed so its tile is linear.
__global__ __launch_bounds__(256, 4) void main_attn_kernel(
    const short* __restrict__ QF, const short* __restrict__ KF,
    const short* __restrict__ V2, const unsigned* __restrict__ MP,
    const float* __restrict__ SW, const float* __restrict__ LSE,
    float* __restrict__ OUT, float* __restrict__ PU, float* __restrict__ PR,
    int nsplit){
  __shared__ __align__(16) short kbuf[2][4096];   // 8KB per buf: [32 t][128] swz
  __shared__ __align__(16) short vbuf[2][4096];   // 8KB per buf: [4 oct][128 d][8 t]
  int lane = threadIdx.x & 63, warp = threadIdx.x >> 6;
  int flat = blockIdx.y * 32 + blockIdx.x;
  int nf = (flat & 7) * 64 + (flat >> 3);         // XCD-chunked (512 % 8 == 0)
  int sblk = nf & 31, h = nf >> 5;
  int split = blockIdx.z;
  int niter = (S_ / 32) / nsplit;
  int tbase = split * (S_ / nsplit);
  int s0 = (sblk * 4 + warp) * 16;
  int col = lane & 15, rg = lane >> 4;

  // Q fragments (B-side): lane holds QF[s0+col][kb*32 + rg*8 ..]
  short8v qa[4];
  const short* qr = QF + ((size_t)h * S_ + s0 + col) * DKER_ + rg * 8;
  #pragma unroll
  for (int kb = 0; kb < 4; ++kb) qa[kb] = *(const short8v*)(qr + kb * 32);

  float4v acc[8];
  #pragma unroll
  for (int j = 0; j < 8; ++j) acc[j] = (float4v){0.f, 0.f, 0.f, 0.f};
  float rs = 0.f;

  // staging addresses
  const char* kf_base = (const char*)(KF + ((size_t)h * S_ + tbase) * DKER_);
  const char* v2_base = (const char*)(V2 + ((size_t)h * (S_/8) + (tbase >> 3)) * DH_ * 8);
  int c0 = warp * 64 + lane, c1 = c0 + 256;
  int kg0 = (c0 * 16) ^ (((c0 >> 4) & 7) << 4);   // pre-swizzled source offset
  int kg1 = (c1 * 16) ^ (((c1 >> 4) & 7) << 4);
  int vg0 = c0 * 16, vg1 = c1 * 16;
  int lds_lo = warp * 512, lds_hi = 2048 + warp * 512;   // short indices

  const float* swrow = SW + ((size_t)h * S_ + s0 + col) * S_ + tbase + rg * 4;
  const unsigned* mpr = MP + ((size_t)h * S_ + s0 + col) * (S_ / 32) + (tbase >> 5);

  // prologue: stage tile 0 into buf 0
  {
    const char* kt = kf_base; const char* vt = v2_base;
    glds16(kt + kg0, &kbuf[0][lds_lo]);
    glds16(kt + kg1, &kbuf[0][lds_hi]);
    glds16(vt + vg0, &vbuf[0][lds_lo]);
    glds16(vt + vg1, &vbuf[0][lds_hi]);
  }
  __syncthreads();

  int swz = (col & 7) << 4;
  int rowb0 = col * 256 + rg * 16;          // byte base, tt=0 row
  int ga = col + ((2 * (rg & 1)) << 4);     // shfl source lanes
  int gb = ga + 16;
  bool hi = (rg >= 2);

  for (int ti = 0; ti < niter; ++ti){
    int cur = ti & 1;
    if (ti + 1 < niter){
      const char* kt = kf_base + (size_t)(ti + 1) * 8192;
      const char* vt = v2_base + (size_t)(ti + 1) * 8192;
      glds16(kt + kg0, &kbuf[cur ^ 1][lds_lo]);
      glds16(kt + kg1, &kbuf[cur ^ 1][lds_hi]);
      glds16(vt + vg0, &vbuf[cur ^ 1][lds_lo]);
      glds16(vt + vg1, &vbuf[cur ^ 1][lds_hi]);
    }
    const char* kbp = (const char*)&kbuf[cur][0];
    const char* vbp = (const char*)&vbuf[cur][0];

    // QK^T swapped: A = KF rows (t), B = Q rows (s).  C: col=s, row=t-rel
    float4v q0 = {0.f,0.f,0.f,0.f}, q1 = {0.f,0.f,0.f,0.f};
    #pragma unroll
    for (int kk = 0; kk < 4; ++kk){
      short8v a0 = *(const short8v*)(kbp + ((rowb0 + kk * 64) ^ swz));
      short8v a1 = *(const short8v*)(kbp + ((rowb0 + 4096 + kk * 64) ^ swz));
      q0 = mfma16(a0, qa[kk], q0);
      q1 = mfma16(a1, qa[kk], q1);
    }

    // P transform (lane owns s=col, t = tbase+ti*32 + {rg*4+r, 16+rg*4+r})
    const float* swp = swrow + ti * 32;
    float4v sv0 = *(const float4v*)swp;
    float4v sv1 = *(const float4v*)(swp + 16);
    unsigned mw = mpr[ti];
    float p0[4], p1[4];
    #pragma unroll
    for (int r = 0; r < 4; ++r){
      bool m0 = (mw >> (rg * 4 + r)) & 1u;
      bool m1 = (mw >> (16 + rg * 4 + r)) & 1u;
      p0[r] = m0 ? (q0[r] + 1e-6f) : expf(sv0[r]);
      p1[r] = m1 ? (q1[r] + 1e-6f) : expf(sv1[r]);
      if (m0) rs += q0[r];
      if (m1) rs += q1[r];
    }
    // pack to bf16 pairs and redistribute to A-fragment layout
    unsigned k00 = cvtpk(p0[0], p0[1]), k01 = cvtpk(p0[2], p0[3]);
    unsigned k10 = cvtpk(p1[0], p1[1]), k11 = cvtpk(p1[2], p1[3]);
    unsigned a0 = __shfl((int)k00, ga), b0 = __shfl((int)k10, ga);
    unsigned a1 = __shfl((int)k01, ga), b1 = __shfl((int)k11, ga);
    unsigned a2 = __shfl((int)k00, gb), b2 = __shfl((int)k10, gb);
    unsigned a3 = __shfl((int)k01, gb), b3 = __shfl((int)k11, gb);
    union { unsigned u[4]; short8v v8; } pw;
    pw.u[0] = hi ? b0 : a0; pw.u[1] = hi ? b1 : a1;
    pw.u[2] = hi ? b2 : a2; pw.u[3] = hi ? b3 : a3;
    short8v pa = pw.v8;

    // PV: B = V[t][d] from linear vbuf [oct=rg][d][8]
    #pragma unroll
    for (int j = 0; j < 8; ++j){
      short8v vf = *(const short8v*)(vbp + rg * 2048 + (j * 16 + col) * 16);
      acc[j] = mfma16(pa, vf, acc[j]);
    }
    __syncthreads();
  }

  // row sums: lane (col, rg) has partial for s=col; reduce across rg groups
  rs += __shfl_xor(rs, 16);
  rs += __shfl_xor(rs, 32);

  if (nsplit == 1){
    float a = logf(rs + 1e-6f);
    float b = LSE[h * S_ + s0 + col];
    float mx = fmaxf(a, b);
    float sc_col = expf(-(mx + log1pf(expf(-fabsf(a - b)))));
    float scale[4];
    #pragma unroll
    for (int r = 0; r < 4; ++r) scale[r] = __shfl(sc_col, rg * 4 + r);
    float* ob = OUT + (size_t)s0 * D_ + h * DH_;
    #pragma unroll
    for (int j = 0; j < 8; ++j)
      #pragma unroll
      for (int r = 0; r < 4; ++r)
        ob[(size_t)(rg * 4 + r) * D_ + j * 16 + col] = acc[j][r] * scale[r];
  } else {
    float* pu = PU + (((size_t)split * H_ + h) * S_ + s0) * DH_;
    #pragma unroll
    for (int j = 0; j < 8; ++j)
      #pragma unroll
      for (int r = 0; r < 4; ++r)
        pu[(size_t)(rg * 4 + r) * DH_ + j * 16 + col] = acc[j][r];
    if (lane < 16)
      PR[((size_t)split * H_ + h) * S_ + s0 + lane] = rs;
  }
}

// Combine split partials: out = (sum U) * exp(-logaddexp(log(sum R + 1e-6), lse))
__global__ __launch_bounds__(256) void reduce_kernel(
    const float* __restrict__ PU, const float* __restrict__ PR,
    const float* __restrict__ LSE, float* __restrict__ OUT, int nsplit){
  size_t gid = (size_t)blockIdx.x * 256 + threadIdx.x;   // over H*S*DH = 2^22
  int d = gid & (DH_ - 1);
  int s = (int)(gid >> 7) & (S_ - 1);
  int h = (int)(gid >> 18);
  float u = 0.f, rr = 0.f;
  for (int i = 0; i < nsplit; ++i){
    u  += PU[(((size_t)i * H_ + h) * S_ + s) * DH_ + d];
    rr += PR[((size_t)i * H_ + h) * S_ + s];
  }
  float a = logf(rr + 1e-6f);
  float b = LSE[h * S_ + s];
  float mx = fmaxf(a, b);
  float norm = mx + log1pf(expf(-fabsf(a - b)));
  OUT[(size_t)s * D_ + h * DH_ + d] = u * expf(-norm);
}

// ---------------------------------------------------------------------------
extern "C" void kernel_launch(void* const* d_in, const int* in_sizes, int n_in,
                              void* d_out, int out_size, void* d_ws, size_t ws_size,
                              hipStream_t stream){
  (void)in_sizes; (void)n_in; (void)out_size;
  const float* q   = (const float*)d_in[1];
  const float* k   = (const float*)d_in[2];
  const float* v   = (const float*)d_in[3];
  const void*  msk = d_in[4];
  const float* lse = (const float*)d_in[5];
  const float* sw  = (const float*)d_in[6];
  const float* w1q = (const float*)d_in[8];
  const float* w1k = (const float*)d_in[9];
  const float* w2q = (const float*)d_in[10];
  const float* w2k = (const float*)d_in[11];
  const float* ik  = (const float*)d_in[12];
  const float* sD  = (const float*)d_in[13];
  const float* sD2 = (const float*)d_in[14];
  float* out = (float*)d_out;

  char* ws = (char*)d_ws;
  size_t o = 0;
  int*   flag = (int*)(ws);            o += 256;
  short* W1qT = (short*)(ws + o);      o += (size_t)H_ * DHID_ * DH_ * 2;
  short* W1kT = (short*)(ws + o);      o += (size_t)H_ * DHID_ * DH_ * 2;
  short* W2qT = (short*)(ws + o);      o += (size_t)H_ * DKER_ * DHID_ * 2;
  short* W2kT = (short*)(ws + o);      o += (size_t)H_ * DKER_ * DHID_ * 2;
  short* IKT  = (short*)(ws + o);      o += (size_t)H_ * DKER_ * DKER_ * 2;
  short* V2   = (short*)(ws + o);      o += (size_t)S_ * D_ * 2;
  short* QFb  = (short*)(ws + o);      o += (size_t)H_ * S_ * DKER_ * 2;
  short* KFb  = (short*)(ws + o);      o += (size_t)H_ * S_ * DKER_ * 2;
  unsigned* MP = (unsigned*)(ws + o);  o += (size_t)H_ * S_ * (S_/32) * 4;
  short* Y = (short*)d_out;            // 16 MB scratch, overwritten later

  size_t per_split = (size_t)H_ * S_ * DH_ * 4 + (size_t)H_ * S_ * 4;
  int nsplit = 1;
  if (ws_size >= o + 4 * per_split)      nsplit = 4;
  else if (ws_size >= o + 2 * per_split) nsplit = 2;
  float* PU = (float*)(ws + o);
  float* PR = PU + (size_t)nsplit * H_ * S_ * DH_;

  detect_mask_kernel<<<1, 256, 0, stream>>>((const unsigned int*)msk, flag);
  pack_mask_kernel<<<(H_*S_*(S_/32))/256, 256, 0, stream>>>(msk, flag, MP);

  dim3 tb(32, 8);
  transpose_bf16_kernel<<<dim3(DHID_/32, DH_/32, H_), tb, 0, stream>>>(w1q, W1qT, DH_, DHID_);
  transpose_bf16_kernel<<<dim3(DHID_/32, DH_/32, H_), tb, 0, stream>>>(w1k, W1kT, DH_, DHID_);
  transpose_bf16_kernel<<<dim3(DKER_/32, DHID_/32, H_), tb, 0, stream>>>(w2q, W2qT, DHID_, DKER_);
  transpose_bf16_kernel<<<dim3(DKER_/32, DHID_/32, H_), tb, 0, stream>>>(w2k, W2kT, DHID_, DKER_);
  transpose_bf16_kernel<<<dim3(DKER_/32, DKER_/32, H_), tb, 0, stream>>>(ik,  IKT,  DKER_, DKER_);
  transpose_v2_kernel<<<dim3(S_/16, H_), 256, 0, stream>>>(v, V2);

  feat1_kernel<<<dim3(S_/64, DHID_/64, H_), 256, 0, stream>>>(q, W1qT, Y);
  feat2q_kernel<<<dim3(S_/64, 1, H_), 256, 0, stream>>>(Y, W2qT, QFb);
  feat1_kernel<<<dim3(S_/64, DHID_/64, H_), 256, 0, stream>>>(k, W1kT, Y);
  feat2k_kernel<<<dim3(S_/64, 1, H_), 256, 0, stream>>>(Y, W2kT, IKT, sD, sD2, KFb);

  main_attn_kernel<<<dim3(32, 16, nsplit), 256, 0, stream>>>(
      QFb, KFb, V2, MP, sw, lse, out, PU, PR, nsplit);
  if (nsplit > 1)
    reduce_kernel<<<(H_*S_*DH_)/256, 256, 0, stream>>>(PU, PR, lse, out, nsplit);
}

// Round 4
// 267.302 us; speedup vs baseline: 2.4308x; 1.1941x over previous
//
#include <hip/hip_runtime.h>
#include <hip/hip_bf16.h>
#include <math.h>

#define H_    16
#define S_    2048
#define D_    2048
#define DH_   128
#define DHID_ 256
#define DKER_ 128

typedef __attribute__((ext_vector_type(8))) short short8v;
typedef __attribute__((ext_vector_type(4))) float float4v;

static __device__ __forceinline__ short f2bf(float x){
  union { float f; unsigned u; } v; v.f = x;
  unsigned r = v.u + 0x7fffu + ((v.u >> 16) & 1u);   // RNE
  return (short)(r >> 16);
}
static __device__ __forceinline__ float gelu_f(float x){
  return 0.5f * x * (1.0f + erff(x * 0.70710678118654752440f));
}
static __device__ __forceinline__ float4v mfma16(short8v a, short8v b, float4v c){
  return __builtin_amdgcn_mfma_f32_16x16x32_bf16(a, b, c, 0, 0, 0);
}
static __device__ __forceinline__ unsigned cvtpk(float lo, float hi){
  unsigned d;
  asm("v_cvt_pk_bf16_f32 %0, %1, %2" : "=v"(d) : "v"(lo), "v"(hi));
  return d;
}
static __device__ __forceinline__ void glds16(const void* g, void* l){
  __builtin_amdgcn_global_load_lds(
      (const __attribute__((address_space(1))) void*)g,
      (__attribute__((address_space(3))) void*)l, 16, 0, 0);
}

// ---------------------------------------------------------------------------
// Mask dtype detection: 0=int32, 1=byte, 2=float32, 3=int64
__global__ void detect_mask_kernel(const unsigned int* mw, int* flag){
  int t = threadIdx.x;
  int bin = 1, f32ok = 1, odd0 = 1;
  for (int i = t; i < 1024; i += 256){
    unsigned w = mw[i];
    if (w > 1u) bin = 0;
    if (w != 0u && w != 0x3F800000u) f32ok = 0;
    if ((i & 1) && w != 0u) odd0 = 0;
  }
  __shared__ int sb, sf, so;
  if (t == 0){ sb = 1; sf = 1; so = 1; }
  __syncthreads();
  if (!bin)  atomicAnd(&sb, 0);
  if (!f32ok) atomicAnd(&sf, 0);
  if (!odd0) atomicAnd(&so, 0);
  __syncthreads();
  if (t == 0) *flag = sb ? (so ? 3 : 0) : (sf ? 2 : 1);
}

// ---------------------------------------------------------------------------
// Consolidated prep: [0,8192) pack_mask; [8192,10240) V2 transpose;
// [10240,12544) weight transposes (W1q, W1k, W2q, W2k, IK).
__global__ __launch_bounds__(256) void prep_kernel(
    const void* __restrict__ mask, const int* __restrict__ flagp,
    unsigned* __restrict__ MP,
    const float* __restrict__ w1q, short* __restrict__ W1qT,
    const float* __restrict__ w1k, short* __restrict__ W1kT,
    const float* __restrict__ w2q, short* __restrict__ W2qT,
    const float* __restrict__ w2k, short* __restrict__ W2kT,
    const float* __restrict__ ik,  short* __restrict__ IKT,
    const float* __restrict__ v,   short* __restrict__ V2){
  __shared__ float tile[32][33];
  int b = blockIdx.x;
  int tid = threadIdx.x;

  if (b < 8192){                      // ---- pack_mask ----
    int flag = *flagp;
    size_t w = (size_t)b * 256 + tid;
    size_t base = w * 32;
    unsigned bits = 0;
    if (flag == 0){
      const int* m = (const int*)mask;
      #pragma unroll
      for (int i = 0; i < 32; ++i) bits |= (m[base + i] != 0 ? 1u : 0u) << i;
    } else if (flag == 1){
      const unsigned char* m = (const unsigned char*)mask;
      #pragma unroll
      for (int i = 0; i < 32; ++i) bits |= (m[base + i] != 0 ? 1u : 0u) << i;
    } else if (flag == 2){
      const float* m = (const float*)mask;
      #pragma unroll
      for (int i = 0; i < 32; ++i) bits |= (m[base + i] != 0.0f ? 1u : 0u) << i;
    } else {
      const int* m = (const int*)mask;   // int64 LE: low word at 2*idx
      #pragma unroll
      for (int i = 0; i < 32; ++i) bits |= (m[2*(base + i)] != 0 ? 1u : 0u) << i;
    }
    MP[w] = bits;
    return;
  }
  b -= 8192;
  if (b < 2048){                      // ---- V2: (h,t,d) -> [h][t/8][d][t&7] ----
    int h = b >> 7, bx = b & 127;
    int d = tid & 127, oct = tid >> 7;
    int t8 = bx * 2 + oct;
    const float* src = v + (size_t)(t8 * 8) * D_ + h * DH_ + d;
    short8v o;
    #pragma unroll
    for (int j = 0; j < 8; ++j) o[j] = f2bf(src[(size_t)j * D_]);
    *(short8v*)(V2 + (((size_t)h * (S_/8) + t8) * DH_ + d) * 8) = o;
    return;
  }
  b -= 2048;                          // ---- weight transposes ----
  const float* src; short* dst; int R, C, bx, by, h;
  if (b < 512){        src = w1q; dst = W1qT; R = DH_;  C = DHID_;
                       bx = b & 7; by = (b >> 3) & 3; h = b >> 5; }
  else if (b < 1024){  b -= 512;  src = w1k; dst = W1kT; R = DH_;  C = DHID_;
                       bx = b & 7; by = (b >> 3) & 3; h = b >> 5; }
  else if (b < 1536){  b -= 1024; src = w2q; dst = W2qT; R = DHID_; C = DKER_;
                       bx = b & 3; by = (b >> 2) & 7; h = b >> 5; }
  else if (b < 2048){  b -= 1536; src = w2k; dst = W2kT; R = DHID_; C = DKER_;
                       bx = b & 3; by = (b >> 2) & 7; h = b >> 5; }
  else {               b -= 2048; src = ik;  dst = IKT;  R = DKER_; C = DKER_;
                       bx = b & 3; by = (b >> 2) & 3; h = b >> 4; }
  int tx = tid & 31, ty = tid >> 5;
  int c0 = bx * 32, r0 = by * 32;
  const float* s = src + (size_t)h * R * C;
  short* d = dst + (size_t)h * R * C;
  #pragma unroll
  for (int i = 0; i < 32; i += 8)
    tile[ty + i][tx] = s[(size_t)(r0 + ty + i) * C + (c0 + tx)];
  __syncthreads();
  #pragma unroll
  for (int i = 0; i < 32; i += 8)
    d[(size_t)(c0 + ty + i) * R + (r0 + tx)] = f2bf(tile[tx][ty + i]);
}

// ---------------------------------------------------------------------------
// Fused per-head 2-layer feature map for q: QF = |gelu(gelu(X@W1)@W2)|
// Y tile (64 s x 256 hid) lives in LDS only.
__global__ __launch_bounds__(256) void featq_kernel(const float* __restrict__ X,
    const short* __restrict__ W1T, const short* __restrict__ W2T,
    short* __restrict__ QF){
  __shared__ __align__(16) short yls[4][16][264];
  int h = blockIdx.y;
  int lane = threadIdx.x & 63, warp = threadIdx.x >> 6;
  int s0 = (blockIdx.x * 4 + warp) * 16;
  int col = lane & 15, rg = lane >> 4;
  short8v a[4];
  {
    const float* xr = X + (size_t)(s0 + col) * D_ + h * DH_;
    #pragma unroll
    for (int kb = 0; kb < 4; ++kb){
      int k0 = kb * 32 + rg * 8;
      float4v x0 = *(const float4v*)(xr + k0);
      float4v x1 = *(const float4v*)(xr + k0 + 4);
      short8v t;
      t[0]=f2bf(x0[0]); t[1]=f2bf(x0[1]); t[2]=f2bf(x0[2]); t[3]=f2bf(x0[3]);
      t[4]=f2bf(x1[0]); t[5]=f2bf(x1[1]); t[6]=f2bf(x1[2]); t[7]=f2bf(x1[3]);
      a[kb] = t;
    }
  }
  const short* wbase = W1T + (size_t)h * DHID_ * DH_;
  #pragma unroll
  for (int j = 0; j < 16; ++j){
    int n = j * 16;
    float4v c = {0.f, 0.f, 0.f, 0.f};
    const short* wr = wbase + (size_t)(n + col) * DH_ + rg * 8;
    #pragma unroll
    for (int kb = 0; kb < 4; ++kb)
      c = mfma16(a[kb], *(const short8v*)(wr + kb * 32), c);
    #pragma unroll
    for (int r = 0; r < 4; ++r)
      yls[warp][rg * 4 + r][n + col] = f2bf(gelu_f(c[r]));
  }
  __syncthreads();
  short8v a2[8];
  #pragma unroll
  for (int kb = 0; kb < 8; ++kb)
    a2[kb] = *(const short8v*)(&yls[warp][col][kb * 32 + rg * 8]);
  const short* wb2 = W2T + (size_t)h * DKER_ * DHID_;
  short* qb = QF + ((size_t)h * S_ + s0) * DKER_;
  #pragma unroll
  for (int j = 0; j < 8; ++j){
    int n = j * 16;
    float4v c = {0.f, 0.f, 0.f, 0.f};
    const short* wr = wb2 + (size_t)(n + col) * DHID_ + rg * 8;
    #pragma unroll
    for (int kb = 0; kb < 8; ++kb)
      c = mfma16(a2[kb], *(const short8v*)(wr + kb * 32), c);
    #pragma unroll
    for (int r = 0; r < 4; ++r)
      qb[(size_t)(rg * 4 + r) * DKER_ + n + col] = f2bf(fabsf(gelu_f(c[r])));
  }
}

// Fused k-side: kf0 = |sD|*gelu(gelu(X@W1)@W2); KF = |kf0 + (kf0@IK)*sD2|
__global__ __launch_bounds__(256) void featk_kernel(const float* __restrict__ X,
    const short* __restrict__ W1T, const short* __restrict__ W2T,
    const short* __restrict__ IKT, const float* __restrict__ sD,
    const float* __restrict__ sD2, short* __restrict__ KF){
  __shared__ __align__(16) short yls[4][16][264];
  int h = blockIdx.y;
  int lane = threadIdx.x & 63, warp = threadIdx.x >> 6;
  int s0 = (blockIdx.x * 4 + warp) * 16;
  int col = lane & 15, rg = lane >> 4;
  short8v a[4];
  {
    const float* xr = X + (size_t)(s0 + col) * D_ + h * DH_;
    #pragma unroll
    for (int kb = 0; kb < 4; ++kb){
      int k0 = kb * 32 + rg * 8;
      float4v x0 = *(const float4v*)(xr + k0);
      float4v x1 = *(const float4v*)(xr + k0 + 4);
      short8v t;
      t[0]=f2bf(x0[0]); t[1]=f2bf(x0[1]); t[2]=f2bf(x0[2]); t[3]=f2bf(x0[3]);
      t[4]=f2bf(x1[0]); t[5]=f2bf(x1[1]); t[6]=f2bf(x1[2]); t[7]=f2bf(x1[3]);
      a[kb] = t;
    }
  }
  const short* wbase = W1T + (size_t)h * DHID_ * DH_;
  #pragma unroll
  for (int j = 0; j < 16; ++j){
    int n = j * 16;
    float4v c = {0.f, 0.f, 0.f, 0.f};
    const short* wr = wbase + (size_t)(n + col) * DH_ + rg * 8;
    #pragma unroll
    for (int kb = 0; kb < 4; ++kb)
      c = mfma16(a[kb], *(const short8v*)(wr + kb * 32), c);
    #pragma unroll
    for (int r = 0; r < 4; ++r)
      yls[warp][rg * 4 + r][n + col] = f2bf(gelu_f(c[r]));
  }
  __syncthreads();
  short8v a2[8];
  #pragma unroll
  for (int kb = 0; kb < 8; ++kb)
    a2[kb] = *(const short8v*)(&yls[warp][col][kb * 32 + rg * 8]);
  const short* wb2 = W2T + (size_t)h * DKER_ * DHID_;
  float kf0[8][4];
  #pragma unroll
  for (int j = 0; j < 8; ++j){
    int n = j * 16;
    float4v c = {0.f, 0.f, 0.f, 0.f};
    const short* wr = wb2 + (size_t)(n + col) * DHID_ + rg * 8;
    #pragma unroll
    for (int kb = 0; kb < 8; ++kb)
      c = mfma16(a2[kb], *(const short8v*)(wr + kb * 32), c);
    float sc = fabsf(sD[h * DKER_ + n + col]);
    #pragma unroll
    for (int r = 0; r < 4; ++r) kf0[j][r] = sc * gelu_f(c[r]);
  }
  __syncthreads();                      // all a2 reads done; reuse yls
  #pragma unroll
  for (int j = 0; j < 8; ++j)
    #pragma unroll
    for (int r = 0; r < 4; ++r)
      yls[warp][rg * 4 + r][j * 16 + col] = f2bf(kf0[j][r]);
  __syncthreads();
  short8v pa[4];
  #pragma unroll
  for (int kb = 0; kb < 4; ++kb)
    pa[kb] = *(const short8v*)(&yls[warp][col][kb * 32 + rg * 8]);
  const short* ib = IKT + (size_t)h * DKER_ * DKER_;
  short* ko = KF + ((size_t)h * S_ + s0) * DKER_;
  #pragma unroll
  for (int j = 0; j < 8; ++j){
    int n = j * 16;
    float4v c = {0.f, 0.f, 0.f, 0.f};
    const short* ir = ib + (size_t)(n + col) * DKER_ + rg * 8;
    #pragma unroll
    for (int kb = 0; kb < 4; ++kb)
      c = mfma16(pa[kb], *(const short8v*)(ir + kb * 32), c);
    float s2 = sD2[h * DKER_ + n + col];
    #pragma unroll
    for (int r = 0; r < 4; ++r)
      ko[(size_t)(rg * 4 + r) * DKER_ + n + col] = f2bf(fabsf(kf0[j][r] + c[r] * s2));
  }
}

// ---------------------------------------------------------------------------
// Fused main pass (unchanged from R3): swapped QK keeps P lane-local; KF/V
// LDS-staged via global_load_lds, double-buffered; KF XOR-swizzled via
// pre-swizzled global source; V2 tile linear.
__global__ __launch_bounds__(256, 4) void main_attn_kernel(
    const short* __restrict__ QF, const short* __restrict__ KF,
    const short* __restrict__ V2, const unsigned* __restrict__ MP,
    const float* __restrict__ SW, const float* __restrict__ LSE,
    float* __restrict__ OUT, float* __restrict__ PU, float* __restrict__ PR,
    int nsplit){
  __shared__ __align__(16) short kbuf[2][4096];
  __shared__ __align__(16) short vbuf[2][4096];
  int lane = threadIdx.x & 63, warp = threadIdx.x >> 6;
  int flat = blockIdx.y * 32 + blockIdx.x;
  int nf = (flat & 7) * 64 + (flat >> 3);         // XCD-chunked (512 % 8 == 0)
  int sblk = nf & 31, h = nf >> 5;
  int split = blockIdx.z;
  int niter = (S_ / 32) / nsplit;
  int tbase = split * (S_ / nsplit);
  int s0 = (sblk * 4 + warp) * 16;
  int col = lane & 15, rg = lane >> 4;

  short8v qa[4];
  const short* qr = QF + ((size_t)h * S_ + s0 + col) * DKER_ + rg * 8;
  #pragma unroll
  for (int kb = 0; kb < 4; ++kb) qa[kb] = *(const short8v*)(qr + kb * 32);

  float4v acc[8];
  #pragma unroll
  for (int j = 0; j < 8; ++j) acc[j] = (float4v){0.f, 0.f, 0.f, 0.f};
  float rs = 0.f;

  const char* kf_base = (const char*)(KF + ((size_t)h * S_ + tbase) * DKER_);
  const char* v2_base = (const char*)(V2 + ((size_t)h * (S_/8) + (tbase >> 3)) * DH_ * 8);
  int c0 = warp * 64 + lane, c1 = c0 + 256;
  int kg0 = (c0 * 16) ^ (((c0 >> 4) & 7) << 4);
  int kg1 = (c1 * 16) ^ (((c1 >> 4) & 7) << 4);
  int vg0 = c0 * 16, vg1 = c1 * 16;
  int lds_lo = warp * 512, lds_hi = 2048 + warp * 512;

  const float* swrow = SW + ((size_t)h * S_ + s0 + col) * S_ + tbase + rg * 4;
  const unsigned* mpr = MP + ((size_t)h * S_ + s0 + col) * (S_ / 32) + (tbase >> 5);

  {
    const char* kt = kf_base; const char* vt = v2_base;
    glds16(kt + kg0, &kbuf[0][lds_lo]);
    glds16(kt + kg1, &kbuf[0][lds_hi]);
    glds16(vt + vg0, &vbuf[0][lds_lo]);
    glds16(vt + vg1, &vbuf[0][lds_hi]);
  }
  __syncthreads();

  int swz = (col & 7) << 4;
  int rowb0 = col * 256 + rg * 16;
  int ga = col + ((2 * (rg & 1)) << 4);
  int gb = ga + 16;
  bool hi = (rg >= 2);

  for (int ti = 0; ti < niter; ++ti){
    int cur = ti & 1;
    if (ti + 1 < niter){
      const char* kt = kf_base + (size_t)(ti + 1) * 8192;
      const char* vt = v2_base + (size_t)(ti + 1) * 8192;
      glds16(kt + kg0, &kbuf[cur ^ 1][lds_lo]);
      glds16(kt + kg1, &kbuf[cur ^ 1][lds_hi]);
      glds16(vt + vg0, &vbuf[cur ^ 1][lds_lo]);
      glds16(vt + vg1, &vbuf[cur ^ 1][lds_hi]);
    }
    const char* kbp = (const char*)&kbuf[cur][0];
    const char* vbp = (const char*)&vbuf[cur][0];

    float4v q0 = {0.f,0.f,0.f,0.f}, q1 = {0.f,0.f,0.f,0.f};
    #pragma unroll
    for (int kk = 0; kk < 4; ++kk){
      short8v a0 = *(const short8v*)(kbp + ((rowb0 + kk * 64) ^ swz));
      short8v a1 = *(const short8v*)(kbp + ((rowb0 + 4096 + kk * 64) ^ swz));
      q0 = mfma16(a0, qa[kk], q0);
      q1 = mfma16(a1, qa[kk], q1);
    }

    const float* swp = swrow + ti * 32;
    float4v sv0 = *(const float4v*)swp;
    float4v sv1 = *(const float4v*)(swp + 16);
    unsigned mw = mpr[ti];
    float p0[4], p1[4];
    #pragma unroll
    for (int r = 0; r < 4; ++r){
      bool m0 = (mw >> (rg * 4 + r)) & 1u;
      bool m1 = (mw >> (16 + rg * 4 + r)) & 1u;
      p0[r] = m0 ? (q0[r] + 1e-6f) : expf(sv0[r]);
      p1[r] = m1 ? (q1[r] + 1e-6f) : expf(sv1[r]);
      if (m0) rs += q0[r];
      if (m1) rs += q1[r];
    }
    unsigned k00 = cvtpk(p0[0], p0[1]), k01 = cvtpk(p0[2], p0[3]);
    unsigned k10 = cvtpk(p1[0], p1[1]), k11 = cvtpk(p1[2], p1[3]);
    unsigned a0 = __shfl((int)k00, ga), b0 = __shfl((int)k10, ga);
    unsigned a1 = __shfl((int)k01, ga), b1 = __shfl((int)k11, ga);
    unsigned a2 = __shfl((int)k00, gb), b2 = __shfl((int)k10, gb);
    unsigned a3 = __shfl((int)k01, gb), b3 = __shfl((int)k11, gb);
    union { unsigned u[4]; short8v v8; } pw;
    pw.u[0] = hi ? b0 : a0; pw.u[1] = hi ? b1 : a1;
    pw.u[2] = hi ? b2 : a2; pw.u[3] = hi ? b3 : a3;
    short8v pa = pw.v8;

    #pragma unroll
    for (int j = 0; j < 8; ++j){
      short8v vf = *(const short8v*)(vbp + rg * 2048 + (j * 16 + col) * 16);
      acc[j] = mfma16(pa, vf, acc[j]);
    }
    __syncthreads();
  }

  rs += __shfl_xor(rs, 16);
  rs += __shfl_xor(rs, 32);

  if (nsplit == 1){
    float a = logf(rs + 1e-6f);
    float b = LSE[h * S_ + s0 + col];
    float mx = fmaxf(a, b);
    float sc_col = expf(-(mx + log1pf(expf(-fabsf(a - b)))));
    float scale[4];
    #pragma unroll
    for (int r = 0; r < 4; ++r) scale[r] = __shfl(sc_col, rg * 4 + r);
    float* ob = OUT + (size_t)s0 * D_ + h * DH_;
    #pragma unroll
    for (int j = 0; j < 8; ++j)
      #pragma unroll
      for (int r = 0; r < 4; ++r)
        ob[(size_t)(rg * 4 + r) * D_ + j * 16 + col] = acc[j][r] * scale[r];
  } else {
    float* pu = PU + (((size_t)split * H_ + h) * S_ + s0) * DH_;
    #pragma unroll
    for (int j = 0; j < 8; ++j)
      #pragma unroll
      for (int r = 0; r < 4; ++r)
        pu[(size_t)(rg * 4 + r) * DH_ + j * 16 + col] = acc[j][r];
    if (lane < 16)
      PR[((size_t)split * H_ + h) * S_ + s0 + lane] = rs;
  }
}

// Combine split partials (vectorized float4), apply exp(-logaddexp(...))
__global__ __launch_bounds__(256) void reduce_kernel(
    const float* __restrict__ PU, const float* __restrict__ PR,
    const float* __restrict__ LSE, float* __restrict__ OUT, int nsplit){
  size_t gid = (size_t)blockIdx.x * 256 + threadIdx.x;   // over H*S*DH/4 = 2^20
  int d4 = (int)(gid & 31);
  int s  = (int)(gid >> 5) & (S_ - 1);
  int h  = (int)(gid >> 16);
  float4v u = {0.f, 0.f, 0.f, 0.f};
  float rr = 0.f;
  for (int i = 0; i < nsplit; ++i){
    u  += *(const float4v*)(PU + (((size_t)i * H_ + h) * S_ + s) * DH_ + d4 * 4);
    rr += PR[((size_t)i * H_ + h) * S_ + s];
  }
  float a = logf(rr + 1e-6f);
  float b = LSE[h * S_ + s];
  float mx = fmaxf(a, b);
  float sc = expf(-(mx + log1pf(expf(-fabsf(a - b)))));
  *(float4v*)(OUT + (size_t)s * D_ + h * DH_ + d4 * 4) = u * sc;
}

// ---------------------------------------------------------------------------
extern "C" void kernel_launch(void* const* d_in, const int* in_sizes, int n_in,
                              void* d_out, int out_size, void* d_ws, size_t ws_size,
                              hipStream_t stream){
  (void)in_sizes; (void)n_in; (void)out_size;
  const float* q   = (const float*)d_in[1];
  const float* k   = (const float*)d_in[2];
  const float* v   = (const float*)d_in[3];
  const void*  msk = d_in[4];
  const float* lse = (const float*)d_in[5];
  const float* sw  = (const float*)d_in[6];
  const float* w1q = (const float*)d_in[8];
  const float* w1k = (const float*)d_in[9];
  const float* w2q = (const float*)d_in[10];
  const float* w2k = (const float*)d_in[11];
  const float* ik  = (const float*)d_in[12];
  const float* sD  = (const float*)d_in[13];
  const float* sD2 = (const float*)d_in[14];
  float* out = (float*)d_out;

  char* ws = (char*)d_ws;
  size_t o = 0;
  int*   flag = (int*)(ws);            o += 256;
  short* W1qT = (short*)(ws + o);      o += (size_t)H_ * DHID_ * DH_ * 2;
  short* W1kT = (short*)(ws + o);      o += (size_t)H_ * DHID_ * DH_ * 2;
  short* W2qT = (short*)(ws + o);      o += (size_t)H_ * DKER_ * DHID_ * 2;
  short* W2kT = (short*)(ws + o);      o += (size_t)H_ * DKER_ * DHID_ * 2;
  short* IKT  = (short*)(ws + o);      o += (size_t)H_ * DKER_ * DKER_ * 2;
  short* V2   = (short*)(ws + o);      o += (size_t)S_ * D_ * 2;
  short* QFb  = (short*)(ws + o);      o += (size_t)H_ * S_ * DKER_ * 2;
  short* KFb  = (short*)(ws + o);      o += (size_t)H_ * S_ * DKER_ * 2;
  unsigned* MP = (unsigned*)(ws + o);  o += (size_t)H_ * S_ * (S_/32) * 4;

  size_t per_split = (size_t)H_ * S_ * DH_ * 4 + (size_t)H_ * S_ * 4;
  int nsplit = (ws_size >= o + 2 * per_split) ? 2 : 1;
  float* PU = (float*)(ws + o);
  float* PR = PU + (size_t)nsplit * H_ * S_ * DH_;

  detect_mask_kernel<<<1, 256, 0, stream>>>((const unsigned int*)msk, flag);
  prep_kernel<<<12544, 256, 0, stream>>>(msk, flag, MP,
      w1q, W1qT, w1k, W1kT, w2q, W2qT, w2k, W2kT, ik, IKT, v, V2);

  featq_kernel<<<dim3(S_/64, H_), 256, 0, stream>>>(q, W1qT, W2qT, QFb);
  featk_kernel<<<dim3(S_/64, H_), 256, 0, stream>>>(k, W1kT, W2kT, IKT, sD, sD2, KFb);

  main_attn_kernel<<<dim3(32, 16, nsplit), 256, 0, stream>>>(
      QFb, KFb, V2, MP, sw, lse, out, PU, PR, nsplit);
  if (nsplit > 1)
    reduce_kernel<<<(H_*S_*DH_/4)/256, 256, 0, stream>>>(PU, PR, lse, out, nsplit);
}

// Round 5
// 246.542 us; speedup vs baseline: 2.6355x; 1.0842x over previous
//
#include <hip/hip_runtime.h>
#include <hip/hip_bf16.h>
#include <math.h>

#define H_    16
#define S_    2048
#define D_    2048
#define DH_   128
#define DHID_ 256
#define DKER_ 128

typedef __attribute__((ext_vector_type(8))) short short8v;
typedef __attribute__((ext_vector_type(4))) float float4v;

static __device__ __forceinline__ short f2bf(float x){
  union { float f; unsigned u; } v; v.f = x;
  unsigned r = v.u + 0x7fffu + ((v.u >> 16) & 1u);   // RNE
  return (short)(r >> 16);
}
static __device__ __forceinline__ float gelu_f(float x){
  return 0.5f * x * (1.0f + erff(x * 0.70710678118654752440f));
}
static __device__ __forceinline__ float4v mfma16(short8v a, short8v b, float4v c){
  return __builtin_amdgcn_mfma_f32_16x16x32_bf16(a, b, c, 0, 0, 0);
}
static __device__ __forceinline__ unsigned cvtpk(float lo, float hi){
  unsigned d;
  asm("v_cvt_pk_bf16_f32 %0, %1, %2" : "=v"(d) : "v"(lo), "v"(hi));
  return d;
}
static __device__ __forceinline__ void glds16(const void* g, void* l){
  __builtin_amdgcn_global_load_lds(
      (const __attribute__((address_space(1))) void*)g,
      (__attribute__((address_space(3))) void*)l, 16, 0, 0);
}

// ---------------------------------------------------------------------------
// Mask dtype detection: 0=int32, 1=byte, 2=float32, 3=int64
__global__ void detect_mask_kernel(const unsigned int* mw, int* flag){
  int t = threadIdx.x;
  int bin = 1, f32ok = 1, odd0 = 1;
  for (int i = t; i < 1024; i += 256){
    unsigned w = mw[i];
    if (w > 1u) bin = 0;
    if (w != 0u && w != 0x3F800000u) f32ok = 0;
    if ((i & 1) && w != 0u) odd0 = 0;
  }
  __shared__ int sb, sf, so;
  if (t == 0){ sb = 1; sf = 1; so = 1; }
  __syncthreads();
  if (!bin)  atomicAnd(&sb, 0);
  if (!f32ok) atomicAnd(&sf, 0);
  if (!odd0) atomicAnd(&so, 0);
  __syncthreads();
  if (t == 0) *flag = sb ? (so ? 3 : 0) : (sf ? 2 : 1);
}

// ---------------------------------------------------------------------------
// Consolidated prep: [0,8192) pack_mask; [8192,10240) V2 transpose;
// [10240,12544) weight transposes (W1q, W1k, W2q, W2k, IK).
__global__ __launch_bounds__(256) void prep_kernel(
    const void* __restrict__ mask, const int* __restrict__ flagp,
    unsigned* __restrict__ MP,
    const float* __restrict__ w1q, short* __restrict__ W1qT,
    const float* __restrict__ w1k, short* __restrict__ W1kT,
    const float* __restrict__ w2q, short* __restrict__ W2qT,
    const float* __restrict__ w2k, short* __restrict__ W2kT,
    const float* __restrict__ ik,  short* __restrict__ IKT,
    const float* __restrict__ v,   short* __restrict__ V2){
  __shared__ float tile[32][33];
  int b = blockIdx.x;
  int tid = threadIdx.x;

  if (b < 8192){                      // ---- pack_mask ----
    int flag = *flagp;
    size_t w = (size_t)b * 256 + tid;
    size_t base = w * 32;
    unsigned bits = 0;
    if (flag == 0){
      const int* m = (const int*)mask;
      #pragma unroll
      for (int i = 0; i < 32; ++i) bits |= (m[base + i] != 0 ? 1u : 0u) << i;
    } else if (flag == 1){
      const unsigned char* m = (const unsigned char*)mask;
      #pragma unroll
      for (int i = 0; i < 32; ++i) bits |= (m[base + i] != 0 ? 1u : 0u) << i;
    } else if (flag == 2){
      const float* m = (const float*)mask;
      #pragma unroll
      for (int i = 0; i < 32; ++i) bits |= (m[base + i] != 0.0f ? 1u : 0u) << i;
    } else {
      const int* m = (const int*)mask;   // int64 LE: low word at 2*idx
      #pragma unroll
      for (int i = 0; i < 32; ++i) bits |= (m[2*(base + i)] != 0 ? 1u : 0u) << i;
    }
    MP[w] = bits;
    return;
  }
  b -= 8192;
  if (b < 2048){                      // ---- V2: (h,t,d) -> [h][t/8][d][t&7] ----
    int h = b >> 7, bx = b & 127;
    int d = tid & 127, oct = tid >> 7;
    int t8 = bx * 2 + oct;
    const float* src = v + (size_t)(t8 * 8) * D_ + h * DH_ + d;
    short8v o;
    #pragma unroll
    for (int j = 0; j < 8; ++j) o[j] = f2bf(src[(size_t)j * D_]);
    *(short8v*)(V2 + (((size_t)h * (S_/8) + t8) * DH_ + d) * 8) = o;
    return;
  }
  b -= 2048;                          // ---- weight transposes ----
  const float* src; short* dst; int R, C, bx, by, h;
  if (b < 512){        src = w1q; dst = W1qT; R = DH_;  C = DHID_;
                       bx = b & 7; by = (b >> 3) & 3; h = b >> 5; }
  else if (b < 1024){  b -= 512;  src = w1k; dst = W1kT; R = DH_;  C = DHID_;
                       bx = b & 7; by = (b >> 3) & 3; h = b >> 5; }
  else if (b < 1536){  b -= 1024; src = w2q; dst = W2qT; R = DHID_; C = DKER_;
                       bx = b & 3; by = (b >> 2) & 7; h = b >> 5; }
  else if (b < 2048){  b -= 1536; src = w2k; dst = W2kT; R = DHID_; C = DKER_;
                       bx = b & 3; by = (b >> 2) & 7; h = b >> 5; }
  else {               b -= 2048; src = ik;  dst = IKT;  R = DKER_; C = DKER_;
                       bx = b & 3; by = (b >> 2) & 3; h = b >> 4; }
  int tx = tid & 31, ty = tid >> 5;
  int c0 = bx * 32, r0 = by * 32;
  const float* s = src + (size_t)h * R * C;
  short* d = dst + (size_t)h * R * C;
  #pragma unroll
  for (int i = 0; i < 32; i += 8)
    tile[ty + i][tx] = s[(size_t)(r0 + ty + i) * C + (c0 + tx)];
  __syncthreads();
  #pragma unroll
  for (int i = 0; i < 32; i += 8)
    d[(size_t)(c0 + ty + i) * R + (r0 + tx)] = f2bf(tile[tx][ty + i]);
}

// ---------------------------------------------------------------------------
// Fused per-head 2-layer feature map for q: QF = |gelu(gelu(X@W1)@W2)|
__global__ __launch_bounds__(256) void featq_kernel(const float* __restrict__ X,
    const short* __restrict__ W1T, const short* __restrict__ W2T,
    short* __restrict__ QF){
  __shared__ __align__(16) short yls[4][16][264];
  int h = blockIdx.y;
  int lane = threadIdx.x & 63, warp = threadIdx.x >> 6;
  int s0 = (blockIdx.x * 4 + warp) * 16;
  int col = lane & 15, rg = lane >> 4;
  short8v a[4];
  {
    const float* xr = X + (size_t)(s0 + col) * D_ + h * DH_;
    #pragma unroll
    for (int kb = 0; kb < 4; ++kb){
      int k0 = kb * 32 + rg * 8;
      float4v x0 = *(const float4v*)(xr + k0);
      float4v x1 = *(const float4v*)(xr + k0 + 4);
      short8v t;
      t[0]=f2bf(x0[0]); t[1]=f2bf(x0[1]); t[2]=f2bf(x0[2]); t[3]=f2bf(x0[3]);
      t[4]=f2bf(x1[0]); t[5]=f2bf(x1[1]); t[6]=f2bf(x1[2]); t[7]=f2bf(x1[3]);
      a[kb] = t;
    }
  }
  const short* wbase = W1T + (size_t)h * DHID_ * DH_;
  #pragma unroll
  for (int j = 0; j < 16; ++j){
    int n = j * 16;
    float4v c = {0.f, 0.f, 0.f, 0.f};
    const short* wr = wbase + (size_t)(n + col) * DH_ + rg * 8;
    #pragma unroll
    for (int kb = 0; kb < 4; ++kb)
      c = mfma16(a[kb], *(const short8v*)(wr + kb * 32), c);
    #pragma unroll
    for (int r = 0; r < 4; ++r)
      yls[warp][rg * 4 + r][n + col] = f2bf(gelu_f(c[r]));
  }
  __syncthreads();
  short8v a2[8];
  #pragma unroll
  for (int kb = 0; kb < 8; ++kb)
    a2[kb] = *(const short8v*)(&yls[warp][col][kb * 32 + rg * 8]);
  const short* wb2 = W2T + (size_t)h * DKER_ * DHID_;
  short* qb = QF + ((size_t)h * S_ + s0) * DKER_;
  #pragma unroll
  for (int j = 0; j < 8; ++j){
    int n = j * 16;
    float4v c = {0.f, 0.f, 0.f, 0.f};
    const short* wr = wb2 + (size_t)(n + col) * DHID_ + rg * 8;
    #pragma unroll
    for (int kb = 0; kb < 8; ++kb)
      c = mfma16(a2[kb], *(const short8v*)(wr + kb * 32), c);
    #pragma unroll
    for (int r = 0; r < 4; ++r)
      qb[(size_t)(rg * 4 + r) * DKER_ + n + col] = f2bf(fabsf(gelu_f(c[r])));
  }
}

// Fused k-side: kf0 = |sD|*gelu(gelu(X@W1)@W2); KF = |kf0 + (kf0@IK)*sD2|
__global__ __launch_bounds__(256) void featk_kernel(const float* __restrict__ X,
    const short* __restrict__ W1T, const short* __restrict__ W2T,
    const short* __restrict__ IKT, const float* __restrict__ sD,
    const float* __restrict__ sD2, short* __restrict__ KF){
  __shared__ __align__(16) short yls[4][16][264];
  int h = blockIdx.y;
  int lane = threadIdx.x & 63, warp = threadIdx.x >> 6;
  int s0 = (blockIdx.x * 4 + warp) * 16;
  int col = lane & 15, rg = lane >> 4;
  short8v a[4];
  {
    const float* xr = X + (size_t)(s0 + col) * D_ + h * DH_;
    #pragma unroll
    for (int kb = 0; kb < 4; ++kb){
      int k0 = kb * 32 + rg * 8;
      float4v x0 = *(const float4v*)(xr + k0);
      float4v x1 = *(const float4v*)(xr + k0 + 4);
      short8v t;
      t[0]=f2bf(x0[0]); t[1]=f2bf(x0[1]); t[2]=f2bf(x0[2]); t[3]=f2bf(x0[3]);
      t[4]=f2bf(x1[0]); t[5]=f2bf(x1[1]); t[6]=f2bf(x1[2]); t[7]=f2bf(x1[3]);
      a[kb] = t;
    }
  }
  const short* wbase = W1T + (size_t)h * DHID_ * DH_;
  #pragma unroll
  for (int j = 0; j < 16; ++j){
    int n = j * 16;
    float4v c = {0.f, 0.f, 0.f, 0.f};
    const short* wr = wbase + (size_t)(n + col) * DH_ + rg * 8;
    #pragma unroll
    for (int kb = 0; kb < 4; ++kb)
      c = mfma16(a[kb], *(const short8v*)(wr + kb * 32), c);
    #pragma unroll
    for (int r = 0; r < 4; ++r)
      yls[warp][rg * 4 + r][n + col] = f2bf(gelu_f(c[r]));
  }
  __syncthreads();
  short8v a2[8];
  #pragma unroll
  for (int kb = 0; kb < 8; ++kb)
    a2[kb] = *(const short8v*)(&yls[warp][col][kb * 32 + rg * 8]);
  const short* wb2 = W2T + (size_t)h * DKER_ * DHID_;
  float kf0[8][4];
  #pragma unroll
  for (int j = 0; j < 8; ++j){
    int n = j * 16;
    float4v c = {0.f, 0.f, 0.f, 0.f};
    const short* wr = wb2 + (size_t)(n + col) * DHID_ + rg * 8;
    #pragma unroll
    for (int kb = 0; kb < 8; ++kb)
      c = mfma16(a2[kb], *(const short8v*)(wr + kb * 32), c);
    float sc = fabsf(sD[h * DKER_ + n + col]);
    #pragma unroll
    for (int r = 0; r < 4; ++r) kf0[j][r] = sc * gelu_f(c[r]);
  }
  __syncthreads();
  #pragma unroll
  for (int j = 0; j < 8; ++j)
    #pragma unroll
    for (int r = 0; r < 4; ++r)
      yls[warp][rg * 4 + r][j * 16 + col] = f2bf(kf0[j][r]);
  __syncthreads();
  short8v pa[4];
  #pragma unroll
  for (int kb = 0; kb < 4; ++kb)
    pa[kb] = *(const short8v*)(&yls[warp][col][kb * 32 + rg * 8]);
  const short* ib = IKT + (size_t)h * DKER_ * DKER_;
  short* ko = KF + ((size_t)h * S_ + s0) * DKER_;
  #pragma unroll
  for (int j = 0; j < 8; ++j){
    int n = j * 16;
    float4v c = {0.f, 0.f, 0.f, 0.f};
    const short* ir = ib + (size_t)(n + col) * DKER_ + rg * 8;
    #pragma unroll
    for (int kb = 0; kb < 4; ++kb)
      c = mfma16(pa[kb], *(const short8v*)(ir + kb * 32), c);
    float s2 = sD2[h * DKER_ + n + col];
    #pragma unroll
    for (int r = 0; r < 4; ++r)
      ko[(size_t)(rg * 4 + r) * DKER_ + n + col] = f2bf(fabsf(kf0[j][r] + c[r] * s2));
  }
}

// ---------------------------------------------------------------------------
// Fused main pass, 8 waves/block. Warps 0-3 cover t in [0,1024), warps 4-7
// t in [1024,2048), same 64 s-rows. Each half has its own 32KB double-buffered
// KF/V staging region. Final combine through LDS; direct out write (no
// partial round-trip). Swapped-QK keeps P lane-local (cvt_pk + shfl).
__global__ __launch_bounds__(512, 4) void main_attn_kernel(
    const short* __restrict__ QF, const short* __restrict__ KF,
    const short* __restrict__ V2, const unsigned* __restrict__ MP,
    const float* __restrict__ SW, const float* __restrict__ LSE,
    float* __restrict__ OUT){
  __shared__ __align__(16) char smem[65536];
  int tid = threadIdx.x;
  int lane = tid & 63, warp = tid >> 6;
  int hf = warp >> 2, w4 = warp & 3;
  int flat = blockIdx.y * 32 + blockIdx.x;
  int nf = (flat & 7) * 64 + (flat >> 3);     // XCD-chunked (512 % 8 == 0)
  int sblk = nf & 31, h = nf >> 5;
  int tbase = hf * (S_ / 2);
  int s0 = (sblk * 4 + w4) * 16;
  int col = lane & 15, rg = lane >> 4;

  short* kbuf = (short*)(smem + hf * 32768);           // [2][4096]
  short* vbuf = (short*)(smem + hf * 32768 + 16384);   // [2][4096]

  short8v qa[4];
  const short* qr = QF + ((size_t)h * S_ + s0 + col) * DKER_ + rg * 8;
  #pragma unroll
  for (int kb = 0; kb < 4; ++kb) qa[kb] = *(const short8v*)(qr + kb * 32);

  float4v acc[8];
  #pragma unroll
  for (int j = 0; j < 8; ++j) acc[j] = (float4v){0.f, 0.f, 0.f, 0.f};
  float rs = 0.f;

  const char* kf_base = (const char*)(KF + ((size_t)h * S_ + tbase) * DKER_);
  const char* v2_base = (const char*)(V2 + ((size_t)h * (S_/8) + (tbase >> 3)) * DH_ * 8);
  int c0 = w4 * 64 + lane, c1 = c0 + 256;
  int kg0 = (c0 * 16) ^ (((c0 >> 4) & 7) << 4);   // pre-swizzled source
  int kg1 = (c1 * 16) ^ (((c1 >> 4) & 7) << 4);
  int vg0 = c0 * 16, vg1 = c1 * 16;
  int lds_lo = w4 * 512, lds_hi = 2048 + w4 * 512;  // short indices (wave-uniform)

  const float* swrow = SW + ((size_t)h * S_ + s0 + col) * S_ + tbase + rg * 4;
  const unsigned* mpr = MP + ((size_t)h * S_ + s0 + col) * (S_ / 32) + (tbase >> 5);

  {
    glds16(kf_base + kg0, &kbuf[lds_lo]);
    glds16(kf_base + kg1, &kbuf[lds_hi]);
    glds16(v2_base + vg0, &vbuf[lds_lo]);
    glds16(v2_base + vg1, &vbuf[lds_hi]);
  }
  __syncthreads();

  int swz = (col & 7) << 4;
  int rowb0 = col * 256 + rg * 16;
  int ga = col + ((2 * (rg & 1)) << 4);
  int gb = ga + 16;
  bool hi = (rg >= 2);
  const int NITER = (S_ / 2) / 32;    // 32

  for (int ti = 0; ti < NITER; ++ti){
    int cur = ti & 1;
    if (ti + 1 < NITER){
      const char* kt = kf_base + (size_t)(ti + 1) * 8192;
      const char* vt = v2_base + (size_t)(ti + 1) * 8192;
      glds16(kt + kg0, &kbuf[(cur ^ 1) * 4096 + lds_lo]);
      glds16(kt + kg1, &kbuf[(cur ^ 1) * 4096 + lds_hi]);
      glds16(vt + vg0, &vbuf[(cur ^ 1) * 4096 + lds_lo]);
      glds16(vt + vg1, &vbuf[(cur ^ 1) * 4096 + lds_hi]);
    }
    const char* kbp = (const char*)kbuf + cur * 8192;
    const char* vbp = (const char*)vbuf + cur * 8192;

    float4v q0 = {0.f,0.f,0.f,0.f}, q1 = {0.f,0.f,0.f,0.f};
    #pragma unroll
    for (int kk = 0; kk < 4; ++kk){
      short8v a0 = *(const short8v*)(kbp + ((rowb0 + kk * 64) ^ swz));
      short8v a1 = *(const short8v*)(kbp + ((rowb0 + 4096 + kk * 64) ^ swz));
      q0 = mfma16(a0, qa[kk], q0);
      q1 = mfma16(a1, qa[kk], q1);
    }

    const float* swp = swrow + ti * 32;
    float4v sv0 = *(const float4v*)swp;
    float4v sv1 = *(const float4v*)(swp + 16);
    unsigned mw = mpr[ti];
    float p0[4], p1[4];
    #pragma unroll
    for (int r = 0; r < 4; ++r){
      bool m0 = (mw >> (rg * 4 + r)) & 1u;
      bool m1 = (mw >> (16 + rg * 4 + r)) & 1u;
      p0[r] = m0 ? (q0[r] + 1e-6f) : __expf(sv0[r]);
      p1[r] = m1 ? (q1[r] + 1e-6f) : __expf(sv1[r]);
      if (m0) rs += q0[r];
      if (m1) rs += q1[r];
    }
    unsigned k00 = cvtpk(p0[0], p0[1]), k01 = cvtpk(p0[2], p0[3]);
    unsigned k10 = cvtpk(p1[0], p1[1]), k11 = cvtpk(p1[2], p1[3]);
    unsigned a0 = __shfl((int)k00, ga), b0 = __shfl((int)k10, ga);
    unsigned a1 = __shfl((int)k01, ga), b1 = __shfl((int)k11, ga);
    unsigned a2 = __shfl((int)k00, gb), b2 = __shfl((int)k10, gb);
    unsigned a3 = __shfl((int)k01, gb), b3 = __shfl((int)k11, gb);
    union { unsigned u[4]; short8v v8; } pw;
    pw.u[0] = hi ? b0 : a0; pw.u[1] = hi ? b1 : a1;
    pw.u[2] = hi ? b2 : a2; pw.u[3] = hi ? b3 : a3;
    short8v pa = pw.v8;

    #pragma unroll
    for (int j = 0; j < 8; ++j){
      short8v vf = *(const short8v*)(vbp + rg * 2048 + (j * 16 + col) * 16);
      acc[j] = mfma16(pa, vf, acc[j]);
    }
    __syncthreads();
  }

  // in-warp row-sum reduce: lanes with equal col end with the col's sum
  rs += __shfl_xor(rs, 16);
  rs += __shfl_xor(rs, 32);

  // ---- cross-half combine through LDS (staging buffers are dead now) ----
  __syncthreads();
  float* cb = (float*)smem;                    // [4][16][128]
  float* rb = (float*)(smem + 32768);          // [4][16]
  if (hf == 1){
    float* cw = cb + (size_t)w4 * 16 * 128;
    #pragma unroll
    for (int j = 0; j < 8; ++j)
      #pragma unroll
      for (int r = 0; r < 4; ++r)
        cw[(size_t)(rg * 4 + r) * 128 + j * 16 + col] = acc[j][r];
    if (lane < 16) rb[w4 * 16 + lane] = rs;
  }
  __syncthreads();
  if (hf == 0){
    float* cw = cb + (size_t)w4 * 16 * 128;
    #pragma unroll
    for (int j = 0; j < 8; ++j)
      #pragma unroll
      for (int r = 0; r < 4; ++r)
        acc[j][r] += cw[(size_t)(rg * 4 + r) * 128 + j * 16 + col];
    rs += rb[w4 * 16 + col];

    float a = logf(rs + 1e-6f);
    float b = LSE[h * S_ + s0 + col];
    float mx = fmaxf(a, b);
    float sc_col = expf(-(mx + log1pf(expf(-fabsf(a - b)))));
    float scale[4];
    #pragma unroll
    for (int r = 0; r < 4; ++r) scale[r] = __shfl(sc_col, rg * 4 + r);
    float* ob = OUT + (size_t)s0 * D_ + h * DH_;
    #pragma unroll
    for (int j = 0; j < 8; ++j)
      #pragma unroll
      for (int r = 0; r < 4; ++r)
        ob[(size_t)(rg * 4 + r) * D_ + j * 16 + col] = acc[j][r] * scale[r];
  }
}

// ---------------------------------------------------------------------------
extern "C" void kernel_launch(void* const* d_in, const int* in_sizes, int n_in,
                              void* d_out, int out_size, void* d_ws, size_t ws_size,
                              hipStream_t stream){
  (void)in_sizes; (void)n_in; (void)out_size; (void)ws_size;
  const float* q   = (const float*)d_in[1];
  const float* k   = (const float*)d_in[2];
  const float* v   = (const float*)d_in[3];
  const void*  msk = d_in[4];
  const float* lse = (const float*)d_in[5];
  const float* sw  = (const float*)d_in[6];
  const float* w1q = (const float*)d_in[8];
  const float* w1k = (const float*)d_in[9];
  const float* w2q = (const float*)d_in[10];
  const float* w2k = (const float*)d_in[11];
  const float* ik  = (const float*)d_in[12];
  const float* sD  = (const float*)d_in[13];
  const float* sD2 = (const float*)d_in[14];
  float* out = (float*)d_out;

  char* ws = (char*)d_ws;
  size_t o = 0;
  int*   flag = (int*)(ws);            o += 256;
  short* W1qT = (short*)(ws + o);      o += (size_t)H_ * DHID_ * DH_ * 2;
  short* W1kT = (short*)(ws + o);      o += (size_t)H_ * DHID_ * DH_ * 2;
  short* W2qT = (short*)(ws + o);      o += (size_t)H_ * DKER_ * DHID_ * 2;
  short* W2kT = (short*)(ws + o);      o += (size_t)H_ * DKER_ * DHID_ * 2;
  short* IKT  = (short*)(ws + o);      o += (size_t)H_ * DKER_ * DKER_ * 2;
  short* V2   = (short*)(ws + o);      o += (size_t)S_ * D_ * 2;
  short* QFb  = (short*)(ws + o);      o += (size_t)H_ * S_ * DKER_ * 2;
  short* KFb  = (short*)(ws + o);      o += (size_t)H_ * S_ * DKER_ * 2;
  unsigned* MP = (unsigned*)(ws + o);  o += (size_t)H_ * S_ * (S_/32) * 4;

  detect_mask_kernel<<<1, 256, 0, stream>>>((const unsigned int*)msk, flag);
  prep_kernel<<<12544, 256, 0, stream>>>(msk, flag, MP,
      w1q, W1qT, w1k, W1kT, w2q, W2qT, w2k, W2kT, ik, IKT, v, V2);

  featq_kernel<<<dim3(S_/64, H_), 256, 0, stream>>>(q, W1qT, W2qT, QFb);
  featk_kernel<<<dim3(S_/64, H_), 256, 0, stream>>>(k, W1kT, W2kT, IKT, sD, sD2, KFb);

  main_attn_kernel<<<dim3(32, 16), 512, 0, stream>>>(
      QFb, KFb, V2, MP, sw, lse, out);
}